// Round 4
// baseline (1406.034 us; speedup 1.0000x reference)
//
#include <hip/hip_runtime.h>
#include <math.h>

#define N_NODES 50000
#define N_EDGES 600000
#define NFEAT   256
#define NHID    128
#define NCLASS  40
#define NB2   782            // bucket = dst >> 6 : one 64-node GEMM tile per bucket
#define CAP2  1024           // staging cap per bucket (mean 767, sigma ~28, +9 sigma)
#define EPB_A 2048           // edges per binning block
#define BINA_BLOCKS ((N_EDGES + EPB_A - 1) / EPB_A)   // 293
#define CVTW_BLOCKS 224                               // 57344 weight elems / 256
#define GEMM_BLOCKS ((N_NODES + 63) / 64)             // 782
#define ACCW 132             // 128 + 4 pad: kills 16-way LDS bank conflict on b128 reads

typedef __attribute__((ext_vector_type(8))) short bf16x8;
typedef __attribute__((ext_vector_type(4))) float f32x4;

__device__ inline ushort f2bf(float f) {   // RNE, finite inputs
    uint u = __float_as_uint(f);
    uint r = (u + 0x7fffu + ((u >> 16) & 1u)) >> 16;
    return (ushort)r;
}

// ---------------------------------------------------------------------------
// K1: blocks [0, BINA_BLOCKS) bin edges by 64-node bucket into fixed-capacity
// staging (record: uint = (bf16(w)<<16) | src; entry {rec, dst&63}).
// Blocks [BINA_BLOCKS, +CVTW_BLOCKS) convert weights to transposed bf16.
__global__ __launch_bounds__(256) void binA_cvtw(const int* __restrict__ src,
                                                 const int* __restrict__ dst,
                                                 const float* __restrict__ w,
                                                 int* __restrict__ bucket_cnt,
                                                 int2* __restrict__ staging, int E,
                                                 const float* __restrict__ W1,
                                                 const float* __restrict__ W2,
                                                 const float* __restrict__ W3,
                                                 ushort* __restrict__ BT1,
                                                 ushort* __restrict__ BT2,
                                                 ushort* __restrict__ BT3) {
    int tid = threadIdx.x;
    if ((int)blockIdx.x >= BINA_BLOCKS) {
        int idx = ((int)blockIdx.x - BINA_BLOCKS) * 256 + tid;
        if (idx < 32768) {                       // BT1: 128x256 from W1[256x128]
            int nr = idx >> 8, k = idx & 255;
            BT1[idx] = f2bf(W1[(size_t)k * 128 + nr]);
        } else if (idx < 49152) {                // BT2: 128x128 from W2[128x128]
            int t = idx - 32768;
            int nr = t >> 7, k = t & 127;
            BT2[t] = f2bf(W2[(size_t)k * 128 + nr]);
        } else if (idx < 57344) {                // BT3: 64x128 from W3[128x40], zero-pad
            int t = idx - 49152;
            int nr = t >> 7, k = t & 127;
            BT3[t] = (nr < 40) ? f2bf(W3[(size_t)k * 40 + nr]) : (ushort)0;
        }
        return;
    }
    __shared__ int lh[NB2];
    for (int b = tid; b < NB2; b += 256) lh[b] = 0;
    __syncthreads();
    int base = blockIdx.x * EPB_A;
    int d[8];
    #pragma unroll
    for (int j = 0; j < 8; ++j) {
        int i = base + j * 256 + tid;
        d[j] = (i < E) ? dst[i] : -1;
        if (d[j] >= 0) atomicAdd(&lh[d[j] >> 6], 1);
    }
    __syncthreads();
    for (int b = tid; b < NB2; b += 256) {
        int c = lh[b];
        lh[b] = c ? (b * CAP2 + atomicAdd(&bucket_cnt[b], c)) : 0;
    }
    __syncthreads();
    #pragma unroll
    for (int j = 0; j < 8; ++j) {
        int i = base + j * 256 + tid;
        if (d[j] >= 0) {
            int slot = atomicAdd(&lh[d[j] >> 6], 1);
            uint rec = ((uint)f2bf(w[i]) << 16) | (uint)src[i];
            staging[slot] = make_int2((int)rec, d[j] & 63);
        }
    }
}

// ---------------------------------------------------------------------------
// bf16 MFMA GEMM (global A), used for GEMM1 only. PACK: feature f stored at
// ushort (f&63)*2 + (f>>6), so one uint = features (l, l+64) for gather lane l.
template<int NT, bool AF32, bool PACK>
__global__ __launch_bounds__(256) void gemm_mfma(const void* __restrict__ Ain,
                                                 const ushort* __restrict__ BT,
                                                 int M, int K, int Nout,
                                                 ushort* __restrict__ Cout) {
    __shared__ ushort a_s[64 * 40];
    __shared__ ushort b_s[64 * NT * 40];
    int tid = threadIdx.x;
    int wave = tid >> 6, lane = tid & 63;
    int lr = lane & 15, lk = (lane >> 4) * 8;
    int row0 = blockIdx.x * 64;
    f32x4 acc[4][NT];
    #pragma unroll
    for (int mt = 0; mt < 4; ++mt)
        #pragma unroll
        for (int nt = 0; nt < NT; ++nt) acc[mt][nt] = (f32x4){0.f, 0.f, 0.f, 0.f};

    for (int k0 = 0; k0 < K; k0 += 32) {
        {   // A tile: 64 rows x 32 k
            int r = tid >> 2, c8 = (tid & 3) * 8;
            int gr = row0 + r; if (gr >= M) gr = M - 1;
            if (AF32) {
                const float* Af = (const float*)Ain;
                float4 v0 = *(const float4*)(Af + (size_t)gr * K + k0 + c8);
                float4 v1 = *(const float4*)(Af + (size_t)gr * K + k0 + c8 + 4);
                ushort4 o0, o1;
                o0.x = f2bf(v0.x); o0.y = f2bf(v0.y); o0.z = f2bf(v0.z); o0.w = f2bf(v0.w);
                o1.x = f2bf(v1.x); o1.y = f2bf(v1.y); o1.z = f2bf(v1.z); o1.w = f2bf(v1.w);
                *(ushort4*)(a_s + r * 40 + c8) = o0;
                *(ushort4*)(a_s + r * 40 + c8 + 4) = o1;
            } else {
                const ushort* Ab = (const ushort*)Ain;
                float4 v = *(const float4*)(Ab + (size_t)gr * K + k0 + c8);
                *(float4*)(a_s + r * 40 + c8) = v;
            }
        }
        #pragma unroll
        for (int i = 0; i < NT; ++i) {
            int idx = tid * NT + i;
            int r = idx >> 2, c8 = (idx & 3) * 8;
            float4 v = *(const float4*)(BT + (size_t)r * K + k0 + c8);
            *(float4*)(b_s + r * 40 + c8) = v;
        }
        __syncthreads();
        bf16x8 bfr[NT];
        #pragma unroll
        for (int nt = 0; nt < NT; ++nt)
            bfr[nt] = *(const bf16x8*)(b_s + ((wave * NT + nt) * 16 + lr) * 40 + lk);
        #pragma unroll
        for (int mt = 0; mt < 4; ++mt) {
            bf16x8 afr = *(const bf16x8*)(a_s + (mt * 16 + lr) * 40 + lk);
            #pragma unroll
            for (int nt = 0; nt < NT; ++nt)
                acc[mt][nt] = __builtin_amdgcn_mfma_f32_16x16x32_bf16(
                    afr, bfr[nt], acc[mt][nt], 0, 0, 0);
        }
        __syncthreads();
    }
    int col0 = wave * NT * 16;
    #pragma unroll
    for (int mt = 0; mt < 4; ++mt) {
        int gr0 = row0 + mt * 16 + (lane >> 4) * 4;
        #pragma unroll
        for (int nt = 0; nt < NT; ++nt) {
            int gc = col0 + nt * 16 + lr;
            #pragma unroll
            for (int i = 0; i < 4; ++i) {
                int gr = gr0 + i;
                if (gr < M && gc < Nout) {
                    int ci = PACK ? ((gc & 63) * 2 + (gc >> 6)) : gc;
                    Cout[(size_t)gr * Nout + ci] = f2bf(acc[mt][nt][i]);
                }
            }
        }
    }
}

// ---------------------------------------------------------------------------
// Fused scatter-aggregate + GEMM. Block = bucket = 64 dst nodes = GEMM tile.
// Agg: edges fully parallel; 8 records per vector load, 8 independent
// row-gathers in flight, LDS f32 atomicAdd (2-way bank alias = free).
// Then A-fragments read from the f32 accumulator with fused bias+relu+cvt;
// B read directly from the L2-hot BT. No per-node CSR, no serialization.
template<int NT, bool PACK>
__global__ __launch_bounds__(256) void fused_agg_gemm(const uint* __restrict__ sup,
                                                      const int* __restrict__ bucket_cnt,
                                                      const int2* __restrict__ staging,
                                                      const float* __restrict__ bias,
                                                      const ushort* __restrict__ BT,
                                                      int Nout,
                                                      ushort* __restrict__ Cout) {
    __shared__ __align__(16) float accf[64 * ACCW];
    int tid = threadIdx.x;
    int wave = tid >> 6, lane = tid & 63;
    int b = blockIdx.x;
    for (int i = tid; i < 64 * ACCW; i += 256) accf[i] = 0.f;
    __syncthreads();
    int c = bucket_cnt[b];
    const int2* sp = staging + (size_t)b * CAP2;
    for (int g = wave * 8; g < c; g += 32) {
        int nn = c - g; if (nn > 8) nn = 8;
        int2 r[8];
        if (nn == 8) {
            const int2* q = sp + g;
            #pragma unroll
            for (int j = 0; j < 8; ++j) r[j] = q[j];
        } else {
            #pragma unroll
            for (int j = 0; j < 8; ++j) r[j] = sp[g + (j < nn ? j : 0)];
        }
        uint p[8];
        #pragma unroll
        for (int j = 0; j < 8; ++j)
            p[j] = sup[(size_t)((uint)r[j].x & 0xffffu) * 64 + lane];
        #pragma unroll
        for (int j = 0; j < 8; ++j) {
            if (j < nn) {   // uniform per wave
                float w = __uint_as_float((uint)r[j].x & 0xffff0000u);
                float vx = __uint_as_float(p[j] << 16);          // feature lane
                float vy = __uint_as_float(p[j] & 0xffff0000u);  // feature lane+64
                int node = r[j].y;
                atomicAdd(&accf[node * ACCW + lane], vx * w);
                atomicAdd(&accf[node * ACCW + 64 + lane], vy * w);
            }
        }
    }
    __syncthreads();
    // GEMM: C[64 x Nout] = relu(acc + bias) @ BT^T, K = 128.
    int lr = lane & 15, lkq = lane >> 4;
    f32x4 acc[4][NT];
    #pragma unroll
    for (int mt = 0; mt < 4; ++mt)
        #pragma unroll
        for (int nt = 0; nt < NT; ++nt) acc[mt][nt] = (f32x4){0.f, 0.f, 0.f, 0.f};
    #pragma unroll
    for (int ks = 0; ks < 4; ++ks) {
        int f0 = ks * 32 + lkq * 8;
        float4 bl = *(const float4*)(bias + f0);
        float4 bh = *(const float4*)(bias + f0 + 4);
        bf16x8 bfr[NT];
        #pragma unroll
        for (int nt = 0; nt < NT; ++nt)
            bfr[nt] = *(const bf16x8*)(BT + (size_t)((wave * NT + nt) * 16 + lr) * 128 + f0);
        #pragma unroll
        for (int mt = 0; mt < 4; ++mt) {
            const float* ap = accf + (mt * 16 + lr) * ACCW + f0;
            float4 u0 = *(const float4*)ap;
            float4 u1 = *(const float4*)(ap + 4);
            bf16x8 afr;
            afr[0] = (short)f2bf(fmaxf(u0.x + bl.x, 0.f));
            afr[1] = (short)f2bf(fmaxf(u0.y + bl.y, 0.f));
            afr[2] = (short)f2bf(fmaxf(u0.z + bl.z, 0.f));
            afr[3] = (short)f2bf(fmaxf(u0.w + bl.w, 0.f));
            afr[4] = (short)f2bf(fmaxf(u1.x + bh.x, 0.f));
            afr[5] = (short)f2bf(fmaxf(u1.y + bh.y, 0.f));
            afr[6] = (short)f2bf(fmaxf(u1.z + bh.z, 0.f));
            afr[7] = (short)f2bf(fmaxf(u1.w + bh.w, 0.f));
            #pragma unroll
            for (int nt = 0; nt < NT; ++nt)
                acc[mt][nt] = __builtin_amdgcn_mfma_f32_16x16x32_bf16(
                    afr, bfr[nt], acc[mt][nt], 0, 0, 0);
        }
    }
    int row0 = b * 64;
    int col0 = wave * NT * 16;
    #pragma unroll
    for (int mt = 0; mt < 4; ++mt) {
        int gr0 = row0 + mt * 16 + lkq * 4;
        #pragma unroll
        for (int nt = 0; nt < NT; ++nt) {
            int gc = col0 + nt * 16 + lr;
            #pragma unroll
            for (int i = 0; i < 4; ++i) {
                int gr = gr0 + i;
                if (gr < N_NODES && gc < Nout) {
                    int ci = PACK ? ((gc & 63) * 2 + (gc >> 6)) : gc;
                    Cout[(size_t)gr * Nout + ci] = f2bf(acc[mt][nt][i]);
                }
            }
        }
    }
}

// ---------------------------------------------------------------------------
// Final layer: scatter-aggregate sup3 (F=64, natural layout, cols 40..63 zero)
// + bias + log_softmax over 40 classes. 4 threads per node for the softmax.
__global__ __launch_bounds__(256) void agg64_lsm(const ushort* __restrict__ sup,
                                                 const int* __restrict__ bucket_cnt,
                                                 const int2* __restrict__ staging,
                                                 const float* __restrict__ bias,
                                                 float* __restrict__ out) {
    __shared__ float acc3[64 * 68];
    int tid = threadIdx.x;
    int wave = tid >> 6, lane = tid & 63;
    int b = blockIdx.x;
    for (int i = tid; i < 64 * 68; i += 256) acc3[i] = 0.f;
    __syncthreads();
    int c = bucket_cnt[b];
    const int2* sp = staging + (size_t)b * CAP2;
    for (int g = wave * 8; g < c; g += 32) {
        int nn = c - g; if (nn > 8) nn = 8;
        int2 r[8];
        if (nn == 8) {
            const int2* q = sp + g;
            #pragma unroll
            for (int j = 0; j < 8; ++j) r[j] = q[j];
        } else {
            #pragma unroll
            for (int j = 0; j < 8; ++j) r[j] = sp[g + (j < nn ? j : 0)];
        }
        ushort p[8];
        #pragma unroll
        for (int j = 0; j < 8; ++j)
            p[j] = sup[(size_t)((uint)r[j].x & 0xffffu) * 64 + lane];
        #pragma unroll
        for (int j = 0; j < 8; ++j) {
            if (j < nn) {
                float w = __uint_as_float((uint)r[j].x & 0xffff0000u);
                float v = __uint_as_float((uint)p[j] << 16);
                atomicAdd(&acc3[r[j].y * 68 + lane], v * w);
            }
        }
    }
    __syncthreads();
    int node = tid >> 2, part = tid & 3;       // 4 threads per node, 10 classes each
    int gr = b * 64 + node;
    float vv[10];
    float m = -INFINITY;
    #pragma unroll
    for (int j = 0; j < 10; ++j) {
        int f = part * 10 + j;
        vv[j] = acc3[node * 68 + f] + bias[f];
        m = fmaxf(m, vv[j]);
    }
    m = fmaxf(m, __shfl_xor(m, 1, 64));
    m = fmaxf(m, __shfl_xor(m, 2, 64));
    float s = 0.f;
    #pragma unroll
    for (int j = 0; j < 10; ++j) s += expf(vv[j] - m);
    s += __shfl_xor(s, 1, 64);
    s += __shfl_xor(s, 2, 64);
    float ls = logf(s) + m;
    if (gr < N_NODES) {
        #pragma unroll
        for (int j = 0; j < 10; ++j)
            out[(size_t)gr * 40 + part * 10 + j] = vv[j] - ls;
    }
}

// ---------------------------------------------------------------------------
extern "C" void kernel_launch(void* const* d_in, const int* in_sizes, int n_in,
                              void* d_out, int out_size, void* d_ws, size_t ws_size,
                              hipStream_t stream) {
    const float* x   = (const float*)d_in[0];
    const float* ew  = (const float*)d_in[1];
    const float* W1  = (const float*)d_in[2];
    const float* b1  = (const float*)d_in[3];
    const float* W2  = (const float*)d_in[4];
    const float* b2  = (const float*)d_in[5];
    const float* W3  = (const float*)d_in[6];
    const float* b3  = (const float*)d_in[7];
    const int* esrc  = (const int*)d_in[8];
    const int* edst  = (const int*)d_in[9];
    float* out = (float*)d_out;

    char* ws = (char*)d_ws;
    size_t off = 0;
    auto alloc = [&](size_t bytes) {
        size_t cur = off;
        off += (bytes + 255) & ~(size_t)255;
        return cur;
    };
    int* bucket_cnt = (int*)(ws + alloc(NB2 * sizeof(int)));
    int2* staging = (int2*)(ws + alloc((size_t)NB2 * CAP2 * sizeof(int2)));  // 6.4 MB
    ushort* BT1  = (ushort*)(ws + alloc(128 * 256 * 2));
    ushort* BT2  = (ushort*)(ws + alloc(128 * 128 * 2));
    ushort* BT3  = (ushort*)(ws + alloc(64 * 128 * 2));
    ushort* supA = (ushort*)(ws + alloc((size_t)N_NODES * 128 * 2));   // 12.8 MB
    ushort* supB = (ushort*)(ws + alloc((size_t)N_NODES * 128 * 2));   // 12.8 MB
    ushort* sup3 = (ushort*)(ws + alloc((size_t)N_NODES * 64 * 2));    // 6.4 MB

    hipMemsetAsync(bucket_cnt, 0, NB2 * sizeof(int), stream);
    // K1: edge binning (dst>>6) || weight conversion
    binA_cvtw<<<BINA_BLOCKS + CVTW_BLOCKS, 256, 0, stream>>>(
        esrc, edst, ew, bucket_cnt, staging, N_EDGES, W1, W2, W3, BT1, BT2, BT3);
    // K2: GEMM1  supA = bf16(x) @ W1   (packed feature layout)
    gemm_mfma<2, true, true><<<GEMM_BLOCKS, 256, 0, stream>>>(
        x, BT1, N_NODES, 256, 128, supA);
    // K3: [scatter-agg supA + b1 + relu] @ W2 -> supB (packed)
    fused_agg_gemm<2, true><<<NB2, 256, 0, stream>>>(
        (const uint*)supA, bucket_cnt, staging, b1, BT2, 128, supB);
    // K4: [scatter-agg supB + b2 + relu] @ W3 -> sup3 (F=64 natural, zero-pad cols)
    fused_agg_gemm<1, false><<<NB2, 256, 0, stream>>>(
        (const uint*)supB, bucket_cnt, staging, b2, BT3, 64, sup3);
    // K5: scatter-agg sup3 + b3 + log_softmax -> out
    agg64_lsm<<<NB2, 256, 0, stream>>>(sup3, bucket_cnt, staging, b3, out);
}

// Round 5
// 237.749 us; speedup vs baseline: 5.9139x; 5.9139x over previous
//
#include <hip/hip_runtime.h>
#include <math.h>

#define N_NODES 50000
#define N_EDGES 600000
#define NFEAT   256
#define NHID    128
#define NCLASS  40
#define NBUCK 196            // bucket = dst >> 8 (256-node windows)
#define EPB_A 2048           // edges per phase-A block
#define BUCK_CAP 4096        // staging capacity per bucket (mean ~3062)
#define BUCK_WIN 5888        // fixed CSR window per bucket >= BUCK_CAP + 7*256 (mult of 8)
#define BINA_BLOCKS ((N_EDGES + EPB_A - 1) / EPB_A)   // 293
#define CVTW_BLOCKS 224                               // 57344 weight elems / 256
#define GEMM_BLOCKS ((N_NODES + 63) / 64)             // 782

typedef __attribute__((ext_vector_type(8))) short bf16x8;
typedef __attribute__((ext_vector_type(4))) float f32x4;
typedef __attribute__((ext_vector_type(2))) float f32x2;

__device__ inline ushort f2bf(float f) {   // RNE, finite inputs
    uint u = __float_as_uint(f);
    uint r = (u + 0x7fffu + ((u >> 16) & 1u)) >> 16;
    return (ushort)r;
}

// ---------------------------------------------------------------------------
// K1: blocks [0, BINA_BLOCKS) bin edges by 256-node bucket into fixed-capacity
// staging regions (record: uint = (bf16(w)<<16) | src; entry {rec, dst&255}).
// Blocks [BINA_BLOCKS, +CVTW_BLOCKS) convert the three weight matrices to
// transposed bf16.
__global__ __launch_bounds__(256) void binA_cvtw(const int* __restrict__ src,
                                                 const int* __restrict__ dst,
                                                 const float* __restrict__ w,
                                                 int* __restrict__ bucket_cnt,
                                                 int2* __restrict__ staging, int E,
                                                 const float* __restrict__ W1,
                                                 const float* __restrict__ W2,
                                                 const float* __restrict__ W3,
                                                 ushort* __restrict__ BT1,
                                                 ushort* __restrict__ BT2,
                                                 ushort* __restrict__ BT3) {
    int tid = threadIdx.x;
    if ((int)blockIdx.x >= BINA_BLOCKS) {
        int idx = ((int)blockIdx.x - BINA_BLOCKS) * 256 + tid;
        if (idx < 32768) {                       // BT1: 128x256 from W1[256x128]
            int nr = idx >> 8, k = idx & 255;
            BT1[idx] = f2bf(W1[(size_t)k * 128 + nr]);
        } else if (idx < 49152) {                // BT2: 128x128 from W2[128x128]
            int t = idx - 32768;
            int nr = t >> 7, k = t & 127;
            BT2[t] = f2bf(W2[(size_t)k * 128 + nr]);
        } else if (idx < 57344) {                // BT3: 64x128 from W3[128x40], zero-pad
            int t = idx - 49152;
            int nr = t >> 7, k = t & 127;
            BT3[t] = (nr < 40) ? f2bf(W3[(size_t)k * 40 + nr]) : (ushort)0;
        }
        return;
    }
    __shared__ int lh[NBUCK];
    for (int b = tid; b < NBUCK; b += 256) lh[b] = 0;
    __syncthreads();
    int base = blockIdx.x * EPB_A;
    int d[8];
    #pragma unroll
    for (int j = 0; j < 8; ++j) {
        int i = base + j * 256 + tid;
        d[j] = (i < E) ? dst[i] : -1;
        if (d[j] >= 0) atomicAdd(&lh[d[j] >> 8], 1);
    }
    __syncthreads();
    for (int b = tid; b < NBUCK; b += 256) {
        int c = lh[b];
        lh[b] = c ? (b * BUCK_CAP + atomicAdd(&bucket_cnt[b], c)) : 0;
    }
    __syncthreads();
    #pragma unroll
    for (int j = 0; j < 8; ++j) {
        int i = base + j * 256 + tid;
        if (d[j] >= 0) {
            int slot = atomicAdd(&lh[d[j] >> 8], 1);
            uint rec = ((uint)f2bf(w[i]) << 16) | (uint)src[i];
            staging[slot] = make_int2((int)rec, d[j] & 255);
        }
    }
}

// ---------------------------------------------------------------------------
// bf16 MFMA GEMM body (global-A variant, used for GEMM1 only).
template<int NT, bool AF32>
__device__ __forceinline__ void gemm_body(const void* __restrict__ Ain,
                                          const ushort* __restrict__ BT,
                                          int M, int K, int Nout,
                                          ushort* __restrict__ Cout, int row0) {
    __shared__ ushort a_s[64 * 40];
    __shared__ ushort b_s[64 * NT * 40];
    int tid = threadIdx.x;
    int wave = tid >> 6, lane = tid & 63;
    int lr = lane & 15, lk = (lane >> 4) * 8;
    f32x4 acc[4][NT];
    #pragma unroll
    for (int mt = 0; mt < 4; ++mt)
        #pragma unroll
        for (int nt = 0; nt < NT; ++nt) acc[mt][nt] = (f32x4){0.f, 0.f, 0.f, 0.f};

    for (int k0 = 0; k0 < K; k0 += 32) {
        {   // A tile: 64 rows x 32 k, 8 elems/thread
            int r = tid >> 2, c8 = (tid & 3) * 8;
            int gr = row0 + r; if (gr >= M) gr = M - 1;  // clamp, store-guarded
            if (AF32) {
                const float* Af = (const float*)Ain;
                float4 v0 = *(const float4*)(Af + (size_t)gr * K + k0 + c8);
                float4 v1 = *(const float4*)(Af + (size_t)gr * K + k0 + c8 + 4);
                ushort4 o0, o1;
                o0.x = f2bf(v0.x); o0.y = f2bf(v0.y); o0.z = f2bf(v0.z); o0.w = f2bf(v0.w);
                o1.x = f2bf(v1.x); o1.y = f2bf(v1.y); o1.z = f2bf(v1.z); o1.w = f2bf(v1.w);
                *(ushort4*)(a_s + r * 40 + c8) = o0;
                *(ushort4*)(a_s + r * 40 + c8 + 4) = o1;
            } else {
                const ushort* Ab = (const ushort*)Ain;
                float4 v = *(const float4*)(Ab + (size_t)gr * K + k0 + c8);
                *(float4*)(a_s + r * 40 + c8) = v;
            }
        }
        #pragma unroll
        for (int i = 0; i < NT; ++i) {  // BT tile: 64*NT rows x 32 k
            int idx = tid * NT + i;
            int r = idx >> 2, c8 = (idx & 3) * 8;
            float4 v = *(const float4*)(BT + (size_t)r * K + k0 + c8);
            *(float4*)(b_s + r * 40 + c8) = v;
        }
        __syncthreads();
        bf16x8 bfr[NT];
        #pragma unroll
        for (int nt = 0; nt < NT; ++nt)
            bfr[nt] = *(const bf16x8*)(b_s + ((wave * NT + nt) * 16 + lr) * 40 + lk);
        #pragma unroll
        for (int mt = 0; mt < 4; ++mt) {
            bf16x8 afr = *(const bf16x8*)(a_s + (mt * 16 + lr) * 40 + lk);
            #pragma unroll
            for (int nt = 0; nt < NT; ++nt)
                acc[mt][nt] = __builtin_amdgcn_mfma_f32_16x16x32_bf16(
                    afr, bfr[nt], acc[mt][nt], 0, 0, 0);
        }
        __syncthreads();
    }
    // C/D layout: col = lane&15, row = (lane>>4)*4 + i
    int col0 = wave * NT * 16;
    #pragma unroll
    for (int mt = 0; mt < 4; ++mt) {
        int gr0 = row0 + mt * 16 + (lane >> 4) * 4;
        #pragma unroll
        for (int nt = 0; nt < NT; ++nt) {
            int gc = col0 + nt * 16 + lr;
            #pragma unroll
            for (int i = 0; i < 4; ++i) {
                int gr = gr0 + i;
                if (gr < M && gc < Nout)
                    Cout[(size_t)gr * Nout + gc] = f2bf(acc[mt][nt][i]);
            }
        }
    }
}

// ---------------------------------------------------------------------------
// K2: blocks [0, NBUCK) do self-contained per-bucket scan+scatter into FIXED
// windows (gaps never read -> no global prefix). Blocks [NBUCK, +782) run
// GEMM1 (x fp32 -> supA bf16), overlapping the CSR tail.
__global__ __launch_bounds__(256) void scan_gemm1(const int* __restrict__ bucket_cnt,
                                                  const int2* __restrict__ staging,
                                                  int2* __restrict__ rsp2,
                                                  uint* __restrict__ edges,
                                                  const float* __restrict__ x,
                                                  const ushort* __restrict__ BT1,
                                                  ushort* __restrict__ supA) {
    if ((int)blockIdx.x >= NBUCK) {
        gemm_body<2, true>(x, BT1, N_NODES, 256, 128, supA,
                           ((int)blockIdx.x - NBUCK) * 64);
        return;
    }
    __shared__ int hist[256];
    __shared__ int buf[256];
    __shared__ int lcur[256];
    int tid = threadIdx.x;
    hist[tid] = 0;
    __syncthreads();
    int b = blockIdx.x;
    int c = bucket_cnt[b];
    const int2* st = staging + (size_t)b * BUCK_CAP;
    for (int p = tid; p < c; p += 256) atomicAdd(&hist[st[p].y], 1);
    __syncthreads();
    int v = (hist[tid] + 7) & ~7;   // pad per-node count to multiple of 8
    buf[tid] = v;
    __syncthreads();
    #pragma unroll
    for (int off = 1; off < 256; off <<= 1) {
        int t = (tid >= off) ? buf[tid - off] : 0;
        __syncthreads();
        buf[tid] += t;
        __syncthreads();
    }
    int bb = b * BUCK_WIN;
    int ex = buf[tid] - v + bb;
    int i = b * 256 + tid;
    if (i < N_NODES) rsp2[i] = make_int2(ex, ex + v);
    lcur[tid] = ex;
    __syncthreads();
    int e0 = bb + buf[255];
    for (int p = bb + tid; p < e0; p += 256) edges[p] = 0;   // covers padding
    __syncthreads();
    for (int p = tid; p < c; p += 256) {
        int2 r = st[p];
        int slot = atomicAdd(&lcur[r.y], 1);
        edges[slot] = (uint)r.x;
    }
}

// ---------------------------------------------------------------------------
// Fused [SpMM(F=128) + bias + relu] -> LDS A-tile -> [MFMA GEMM x BT].
// One block = 64 output rows; each wave gathers 16 nodes. ROUND-5 CHANGE:
// the cross-node latency chain is broken by hand: (1) all 16 rsp2 ranges are
// hoisted and loaded upfront (independent loads, one latency window);
// (2) node i+1's first edge-group is prefetched while node i is processed.
// Per-node critical path drops from ~3 dependent loads to ~1.
template<int NT>
__global__ __launch_bounds__(256) void fused_spmm_gemm(const uint* __restrict__ sup,
                                                       const int2* __restrict__ rsp2,
                                                       const uint* __restrict__ edges,
                                                       const float* __restrict__ bias,
                                                       const ushort* __restrict__ BT,
                                                       int Nout,
                                                       ushort* __restrict__ Cout) {
    __shared__ ushort a4_s[4][64 * 40];
    int tid = threadIdx.x;
    int wave = tid >> 6, lane = tid & 63;
    int row0 = blockIdx.x * 64;
    float bx = bias[2 * lane], by = bias[2 * lane + 1];
    int ks = lane >> 4;            // which 32-k subtile this lane's features fall in
    int kk = 2 * (lane & 15);      // k offset within the subtile

    // (1) hoist: all 16 node ranges upfront (wave-uniform broadcast loads)
    int2 ke[16];
    #pragma unroll
    for (int i = 0; i < 16; ++i) {
        int node = row0 + wave * 16 + i;
        int nd = (node < N_NODES) ? node : (N_NODES - 1);  // clamp; store-guarded
        ke[i] = rsp2[nd];
    }
    // (2) prefetch node 0's first edge-group (safe: window padded, alloc'd)
    uint4 fa, fb;
    {
        const uint4* q4 = (const uint4*)(edges + ke[0].x);
        fa = q4[0]; fb = q4[1];
    }
    #pragma unroll 4
    for (int i = 0; i < 16; ++i) {
        int k = ke[i].x, e = ke[i].y;
        uint4 qa = fa, qb = fb;
        if (i < 15) {   // prefetch NEXT node's first group (independent of this node)
            const uint4* q4 = (const uint4*)(edges + ke[i + 1].x);
            fa = q4[0]; fb = q4[1];
        }
        f32x2 acc2 = (f32x2){0.f, 0.f};
        for (; k < e; k += 8) {
            int kn = k + 8;
            int kc = (kn < e) ? kn : k;          // clamp: reload current (L1 hit)
            const uint4* n4 = (const uint4*)(edges + kc);
            uint4 na = n4[0], nb = n4[1];        // rotate-prefetch next group
            uint q[8] = {qa.x, qa.y, qa.z, qa.w, qb.x, qb.y, qb.z, qb.w};
            uint p[8];
            #pragma unroll
            for (int j = 0; j < 8; ++j)
                p[j] = sup[(size_t)(q[j] & 0xffffu) * 64 + lane];
            #pragma unroll
            for (int j = 0; j < 8; ++j) {
                float w = __uint_as_float(q[j] & 0xffff0000u);  // bf16 bits -> f32
                f32x2 v;
                v.x = __uint_as_float(p[j] << 16);
                v.y = __uint_as_float(p[j] & 0xffff0000u);
                acc2 += v * (f32x2){w, w};
            }
            qa = na; qb = nb;
        }
        uint pk = ((uint)f2bf(fmaxf(acc2.y + by, 0.f)) << 16)
                |  (uint)f2bf(fmaxf(acc2.x + bx, 0.f));
        *(uint*)(&a4_s[ks][(wave * 16 + i) * 40 + kk]) = pk;
    }
    __syncthreads();
    // GEMM: C[64 x Nout] = A(LDS) @ BT^T, K = 128.
    int lr = lane & 15, lk = (lane >> 4) * 8;
    f32x4 acc[4][NT];
    #pragma unroll
    for (int mt = 0; mt < 4; ++mt)
        #pragma unroll
        for (int nt = 0; nt < NT; ++nt) acc[mt][nt] = (f32x4){0.f, 0.f, 0.f, 0.f};
    #pragma unroll
    for (int ksi = 0; ksi < 4; ++ksi) {
        int k0 = ksi * 32;
        bf16x8 bfr[NT];
        #pragma unroll
        for (int nt = 0; nt < NT; ++nt)
            bfr[nt] = *(const bf16x8*)(BT +
                (size_t)((wave * NT + nt) * 16 + lr) * 128 + k0 + lk);
        #pragma unroll
        for (int mt = 0; mt < 4; ++mt) {
            bf16x8 afr = *(const bf16x8*)(&a4_s[ksi][(mt * 16 + lr) * 40 + lk]);
            #pragma unroll
            for (int nt = 0; nt < NT; ++nt)
                acc[mt][nt] = __builtin_amdgcn_mfma_f32_16x16x32_bf16(
                    afr, bfr[nt], acc[mt][nt], 0, 0, 0);
        }
    }
    int col0 = wave * NT * 16;
    #pragma unroll
    for (int mt = 0; mt < 4; ++mt) {
        int gr0 = row0 + mt * 16 + (lane >> 4) * 4;
        #pragma unroll
        for (int nt = 0; nt < NT; ++nt) {
            int gc = col0 + nt * 16 + lr;
            #pragma unroll
            for (int i = 0; i < 4; ++i) {
                int gr = gr0 + i;
                if (gr < N_NODES && gc < Nout)
                    Cout[(size_t)gr * Nout + gc] = f2bf(acc[mt][nt][i]);
            }
        }
    }
}

// ---------------------------------------------------------------------------
// Layer 3: bf16 F=40 segment-sum + bias + log_softmax fused -> out (fp32)
__global__ __launch_bounds__(256) void spmm40_lsm(const ushort* __restrict__ sup,
                                                  const int2* __restrict__ rsp2,
                                                  const uint* __restrict__ edges,
                                                  const float* __restrict__ bias,
                                                  float* __restrict__ out, int n) {
    int wid = blockIdx.x * 4 + (threadIdx.x >> 6);
    int lane = threadIdx.x & 63;
    if (wid >= n) return;
    int2 ke = rsp2[wid];
    int k = ke.x, e = ke.y;
    float acc = 0.f;
    int lf = (lane < 40) ? lane : 39;  // inactive lanes read lane 39 (no OOB)
    if (k < e) {
        const uint4* q4 = (const uint4*)(edges + k);
        uint4 qa = q4[0], qb = q4[1];
        for (; k < e; k += 8) {
            int kn = k + 8;
            int kc = (kn < e) ? kn : k;
            const uint4* n4 = (const uint4*)(edges + kc);
            uint4 na = n4[0], nb4 = n4[1];
            uint q[8] = {qa.x, qa.y, qa.z, qa.w, qb.x, qb.y, qb.z, qb.w};
            float p[8];
            #pragma unroll
            for (int j = 0; j < 8; ++j) {
                uint us = sup[(size_t)(q[j] & 0xffffu) * 40 + lf];
                p[j] = __uint_as_float(us << 16);
            }
            #pragma unroll
            for (int j = 0; j < 8; ++j)
                acc += p[j] * __uint_as_float(q[j] & 0xffff0000u);
            qa = na; qb = nb4;
        }
    }
    float v = (lane < 40) ? acc + bias[lane] : -INFINITY;
    float m = v;
    #pragma unroll
    for (int off = 32; off; off >>= 1) m = fmaxf(m, __shfl_xor(m, off, 64));
    float ex = (lane < 40) ? expf(v - m) : 0.f;
    float s = ex;
    #pragma unroll
    for (int off = 32; off; off >>= 1) s += __shfl_xor(s, off, 64);
    float ls = logf(s);
    if (lane < 40) out[(size_t)wid * 40 + lane] = v - m - ls;
}

// ---------------------------------------------------------------------------
extern "C" void kernel_launch(void* const* d_in, const int* in_sizes, int n_in,
                              void* d_out, int out_size, void* d_ws, size_t ws_size,
                              hipStream_t stream) {
    const float* x   = (const float*)d_in[0];
    const float* ew  = (const float*)d_in[1];
    const float* W1  = (const float*)d_in[2];
    const float* b1  = (const float*)d_in[3];
    const float* W2  = (const float*)d_in[4];
    const float* b2  = (const float*)d_in[5];
    const float* W3  = (const float*)d_in[6];
    const float* b3  = (const float*)d_in[7];
    const int* esrc  = (const int*)d_in[8];
    const int* edst  = (const int*)d_in[9];
    float* out = (float*)d_out;

    char* ws = (char*)d_ws;
    size_t off = 0;
    auto alloc = [&](size_t bytes) {
        size_t cur = off;
        off += (bytes + 255) & ~(size_t)255;
        return cur;
    };
    int* bucket_cnt = (int*)(ws + alloc(256 * sizeof(int)));
    int2* rsp2   = (int2*)(ws + alloc((size_t)N_NODES * sizeof(int2)));          // 400 KB
    uint* edges  = (uint*)(ws + alloc((size_t)NBUCK * BUCK_WIN * sizeof(uint))); // 4.6 MB
    int2* staging = (int2*)(ws + alloc((size_t)NBUCK * BUCK_CAP * sizeof(int2))); // 6.4 MB
    ushort* BT1  = (ushort*)(ws + alloc(128 * 256 * 2));
    ushort* BT2  = (ushort*)(ws + alloc(128 * 128 * 2));
    ushort* BT3  = (ushort*)(ws + alloc(64 * 128 * 2));
    char* Sreg   = ws + alloc((size_t)N_NODES * 128 * 2);       // 12.8 MB
    char* Hreg   = ws + alloc((size_t)N_NODES * 128 * 2);       // 12.8 MB

    ushort* supA = (ushort*)Sreg;                  // gemm1 out
    ushort* supB = (ushort*)Hreg;                  // fused ag2 out
    ushort* sup3 = (ushort*)Sreg;                  // fused ag3 out (supA dead), 40/row

    hipMemsetAsync(bucket_cnt, 0, 256 * sizeof(int), stream);
    // K1: edge binning || weight conversion
    binA_cvtw<<<BINA_BLOCKS + CVTW_BLOCKS, 256, 0, stream>>>(
        esrc, edst, ew, bucket_cnt, staging, N_EDGES, W1, W2, W3, BT1, BT2, BT3);
    // K2: per-bucket scan+scatter (fixed windows) || GEMM1
    scan_gemm1<<<NBUCK + GEMM_BLOCKS, 256, 0, stream>>>(
        bucket_cnt, staging, rsp2, edges, x, BT1, supA);
    // K3: [agg1 + b1 + relu] -> GEMM x BT2 -> supB   (hA never hits global)
    fused_spmm_gemm<2><<<GEMM_BLOCKS, 256, 0, stream>>>(
        (const uint*)supA, rsp2, edges, b1, BT2, 128, supB);
    // K4: [agg2 + b2 + relu] -> GEMM x BT3 -> sup3 (40/row)
    fused_spmm_gemm<1><<<GEMM_BLOCKS, 256, 0, stream>>>(
        (const uint*)supB, rsp2, edges, b2, BT3, 40, sup3);
    // K5: agg3 + b3 + log_softmax -> out
    spmm40_lsm<<<(N_NODES + 3) / 4, 256, 0, stream>>>(sup3, rsp2, edges, b3,
                                                      out, N_NODES);
}

// Round 6
// 216.192 us; speedup vs baseline: 6.5036x; 1.0997x over previous
//
#include <hip/hip_runtime.h>
#include <math.h>

#define N_NODES 50000
#define N_EDGES 600000
#define NFEAT   256
#define NHID    128
#define NCLASS  40
#define NBUCK 196            // bucket = dst >> 8 (256-node windows)
#define EPB_A 2048           // edges per phase-A block
#define BUCK_CAP 4096        // staging capacity per bucket (mean ~3062)
#define BUCK_WIN 5888        // fixed CSR window per bucket >= BUCK_CAP + 7*256 (mult of 8)
#define BINA_BLOCKS ((N_EDGES + EPB_A - 1) / EPB_A)   // 293
#define CVTW_BLOCKS 224                               // 57344 weight elems / 256
#define GEMM_BLOCKS ((N_NODES + 63) / 64)             // 782

typedef __attribute__((ext_vector_type(8))) short bf16x8;
typedef __attribute__((ext_vector_type(4))) float f32x4;
typedef __attribute__((ext_vector_type(2))) float f32x2;

__device__ inline ushort f2bf(float f) {   // RNE, finite inputs
    uint u = __float_as_uint(f);
    uint r = (u + 0x7fffu + ((u >> 16) & 1u)) >> 16;
    return (ushort)r;
}

// ---------------------------------------------------------------------------
// K1: blocks [0, BINA_BLOCKS) bin edges by 256-node bucket into fixed-capacity
// staging regions (record: uint = (bf16(w)<<16) | src; entry {rec, dst&255}).
// Blocks [BINA_BLOCKS, +CVTW_BLOCKS) convert the three weight matrices to
// transposed bf16.
__global__ __launch_bounds__(256) void binA_cvtw(const int* __restrict__ src,
                                                 const int* __restrict__ dst,
                                                 const float* __restrict__ w,
                                                 int* __restrict__ bucket_cnt,
                                                 int2* __restrict__ staging, int E,
                                                 const float* __restrict__ W1,
                                                 const float* __restrict__ W2,
                                                 const float* __restrict__ W3,
                                                 ushort* __restrict__ BT1,
                                                 ushort* __restrict__ BT2,
                                                 ushort* __restrict__ BT3) {
    int tid = threadIdx.x;
    if ((int)blockIdx.x >= BINA_BLOCKS) {
        int idx = ((int)blockIdx.x - BINA_BLOCKS) * 256 + tid;
        if (idx < 32768) {                       // BT1: 128x256 from W1[256x128]
            int nr = idx >> 8, k = idx & 255;
            BT1[idx] = f2bf(W1[(size_t)k * 128 + nr]);
        } else if (idx < 49152) {                // BT2: 128x128 from W2[128x128]
            int t = idx - 32768;
            int nr = t >> 7, k = t & 127;
            BT2[t] = f2bf(W2[(size_t)k * 128 + nr]);
        } else if (idx < 57344) {                // BT3: 64x128 from W3[128x40], zero-pad
            int t = idx - 49152;
            int nr = t >> 7, k = t & 127;
            BT3[t] = (nr < 40) ? f2bf(W3[(size_t)k * 40 + nr]) : (ushort)0;
        }
        return;
    }
    __shared__ int lh[NBUCK];
    for (int b = tid; b < NBUCK; b += 256) lh[b] = 0;
    __syncthreads();
    int base = blockIdx.x * EPB_A;
    int d[8];
    #pragma unroll
    for (int j = 0; j < 8; ++j) {
        int i = base + j * 256 + tid;
        d[j] = (i < E) ? dst[i] : -1;
        if (d[j] >= 0) atomicAdd(&lh[d[j] >> 8], 1);
    }
    __syncthreads();
    for (int b = tid; b < NBUCK; b += 256) {
        int c = lh[b];
        lh[b] = c ? (b * BUCK_CAP + atomicAdd(&bucket_cnt[b], c)) : 0;
    }
    __syncthreads();
    #pragma unroll
    for (int j = 0; j < 8; ++j) {
        int i = base + j * 256 + tid;
        if (d[j] >= 0) {
            int slot = atomicAdd(&lh[d[j] >> 8], 1);
            uint rec = ((uint)f2bf(w[i]) << 16) | (uint)src[i];
            staging[slot] = make_int2((int)rec, d[j] & 255);
        }
    }
}

// ---------------------------------------------------------------------------
// bf16 MFMA GEMM body (global-A variant, used for GEMM1 only).
template<int NT, bool AF32>
__device__ __forceinline__ void gemm_body(const void* __restrict__ Ain,
                                          const ushort* __restrict__ BT,
                                          int M, int K, int Nout,
                                          ushort* __restrict__ Cout, int row0) {
    __shared__ ushort a_s[64 * 40];
    __shared__ ushort b_s[64 * NT * 40];
    int tid = threadIdx.x;
    int wave = tid >> 6, lane = tid & 63;
    int lr = lane & 15, lk = (lane >> 4) * 8;
    f32x4 acc[4][NT];
    #pragma unroll
    for (int mt = 0; mt < 4; ++mt)
        #pragma unroll
        for (int nt = 0; nt < NT; ++nt) acc[mt][nt] = (f32x4){0.f, 0.f, 0.f, 0.f};

    for (int k0 = 0; k0 < K; k0 += 32) {
        {   // A tile: 64 rows x 32 k, 8 elems/thread
            int r = tid >> 2, c8 = (tid & 3) * 8;
            int gr = row0 + r; if (gr >= M) gr = M - 1;  // clamp, store-guarded
            if (AF32) {
                const float* Af = (const float*)Ain;
                float4 v0 = *(const float4*)(Af + (size_t)gr * K + k0 + c8);
                float4 v1 = *(const float4*)(Af + (size_t)gr * K + k0 + c8 + 4);
                ushort4 o0, o1;
                o0.x = f2bf(v0.x); o0.y = f2bf(v0.y); o0.z = f2bf(v0.z); o0.w = f2bf(v0.w);
                o1.x = f2bf(v1.x); o1.y = f2bf(v1.y); o1.z = f2bf(v1.z); o1.w = f2bf(v1.w);
                *(ushort4*)(a_s + r * 40 + c8) = o0;
                *(ushort4*)(a_s + r * 40 + c8 + 4) = o1;
            } else {
                const ushort* Ab = (const ushort*)Ain;
                float4 v = *(const float4*)(Ab + (size_t)gr * K + k0 + c8);
                *(float4*)(a_s + r * 40 + c8) = v;
            }
        }
        #pragma unroll
        for (int i = 0; i < NT; ++i) {  // BT tile: 64*NT rows x 32 k
            int idx = tid * NT + i;
            int r = idx >> 2, c8 = (idx & 3) * 8;
            float4 v = *(const float4*)(BT + (size_t)r * K + k0 + c8);
            *(float4*)(b_s + r * 40 + c8) = v;
        }
        __syncthreads();
        bf16x8 bfr[NT];
        #pragma unroll
        for (int nt = 0; nt < NT; ++nt)
            bfr[nt] = *(const bf16x8*)(b_s + ((wave * NT + nt) * 16 + lr) * 40 + lk);
        #pragma unroll
        for (int mt = 0; mt < 4; ++mt) {
            bf16x8 afr = *(const bf16x8*)(a_s + (mt * 16 + lr) * 40 + lk);
            #pragma unroll
            for (int nt = 0; nt < NT; ++nt)
                acc[mt][nt] = __builtin_amdgcn_mfma_f32_16x16x32_bf16(
                    afr, bfr[nt], acc[mt][nt], 0, 0, 0);
        }
        __syncthreads();
    }
    // C/D layout: col = lane&15, row = (lane>>4)*4 + i
    int col0 = wave * NT * 16;
    #pragma unroll
    for (int mt = 0; mt < 4; ++mt) {
        int gr0 = row0 + mt * 16 + (lane >> 4) * 4;
        #pragma unroll
        for (int nt = 0; nt < NT; ++nt) {
            int gc = col0 + nt * 16 + lr;
            #pragma unroll
            for (int i = 0; i < 4; ++i) {
                int gr = gr0 + i;
                if (gr < M && gc < Nout)
                    Cout[(size_t)gr * Nout + gc] = f2bf(acc[mt][nt][i]);
            }
        }
    }
}

// ---------------------------------------------------------------------------
// K2: blocks [0, NBUCK) do self-contained per-bucket scan+scatter into FIXED
// windows (gaps never read -> no global prefix). Blocks [NBUCK, +782) run
// GEMM1 (x fp32 -> supA bf16), overlapping the CSR tail.
__global__ __launch_bounds__(256) void scan_gemm1(const int* __restrict__ bucket_cnt,
                                                  const int2* __restrict__ staging,
                                                  int2* __restrict__ rsp2,
                                                  uint* __restrict__ edges,
                                                  const float* __restrict__ x,
                                                  const ushort* __restrict__ BT1,
                                                  ushort* __restrict__ supA) {
    if ((int)blockIdx.x >= NBUCK) {
        gemm_body<2, true>(x, BT1, N_NODES, 256, 128, supA,
                           ((int)blockIdx.x - NBUCK) * 64);
        return;
    }
    __shared__ int hist[256];
    __shared__ int buf[256];
    __shared__ int lcur[256];
    int tid = threadIdx.x;
    hist[tid] = 0;
    __syncthreads();
    int b = blockIdx.x;
    int c = bucket_cnt[b];
    const int2* st = staging + (size_t)b * BUCK_CAP;
    for (int p = tid; p < c; p += 256) atomicAdd(&hist[st[p].y], 1);
    __syncthreads();
    int v = (hist[tid] + 7) & ~7;   // pad per-node count to multiple of 8
    buf[tid] = v;
    __syncthreads();
    #pragma unroll
    for (int off = 1; off < 256; off <<= 1) {
        int t = (tid >= off) ? buf[tid - off] : 0;
        __syncthreads();
        buf[tid] += t;
        __syncthreads();
    }
    int bb = b * BUCK_WIN;
    int ex = buf[tid] - v + bb;
    int i = b * 256 + tid;
    if (i < N_NODES) rsp2[i] = make_int2(ex, ex + v);
    lcur[tid] = ex;
    __syncthreads();
    int e0 = bb + buf[255];
    for (int p = bb + tid; p < e0; p += 256) edges[p] = 0;   // covers padding
    __syncthreads();
    for (int p = tid; p < c; p += 256) {
        int2 r = st[p];
        int slot = atomicAdd(&lcur[r.y], 1);
        edges[slot] = (uint)r.x;
    }
}

// ---------------------------------------------------------------------------
// Fused [flattened-stream SpMM(F=128) + bias + relu] -> LDS A-tile -> MFMA GEMM.
// ROUND-6: a wave's 16 nodes are CONTIGUOUS in the padded CSR, so the wave
// processes ONE edge stream [Q, QE) in 16-edge chunks with a ping-pong
// pipeline (chunk q FMA || chunk q+16 gathers in flight || chunk q+32 records
// loading) and an advancing flush pointer at node boundaries (ends in LDS,
// all control wave-uniform). Sustained ~16-32 outstanding gathers/wave vs 8.

#define LDREC(Ra, Rb, Rc, Rd, POS) do { \
    const uint4* _p = (const uint4*)(edges + (POS)); \
    Ra = _p[0]; Rb = _p[1]; Rc = _p[2]; Rd = _p[3]; \
} while (0)

#define GATHER(P, W, Ra, Rb, Rc, Rd) do { \
    uint _r[16] = {Ra.x, Ra.y, Ra.z, Ra.w, Rb.x, Rb.y, Rb.z, Rb.w, \
                   Rc.x, Rc.y, Rc.z, Rc.w, Rd.x, Rd.y, Rd.z, Rd.w}; \
    _Pragma("unroll") \
    for (int _j = 0; _j < 16; ++_j) { \
        uint _idx = _r[_j] & 0xffffu; \
        if (_idx >= N_NODES) _idx = N_NODES - 1;  /* garbage-tail safety */ \
        P[_j] = sup[(size_t)_idx * 64 + lane]; \
        W[_j] = __uint_as_float(_r[_j] & 0xffff0000u); \
    } \
} while (0)

#define FLUSH1() do { \
    uint _pk = ((uint)f2bf(fmaxf(acc2.y + by, 0.f)) << 16) \
             |  (uint)f2bf(fmaxf(acc2.x + bx, 0.f)); \
    *(uint*)(&a4_s[ks][(wave * 16 + cur) * 40 + kk]) = _pk; \
    acc2 = (f32x2){0.f, 0.f}; \
    ++cur; \
    e_cur = (cur < 16) ? e_s[wave][cur + 1] : 0x7fffffff; \
} while (0)

#define FMA_CHUNK(QB, P, W) do { \
    _Pragma("unroll") \
    for (int _g = 0; _g < 2; ++_g) { \
        int _qg = (QB) + _g * 8; \
        while (cur < 16 && _qg >= e_cur) FLUSH1(); \
        if (_qg < QE) { \
            _Pragma("unroll") \
            for (int _j = 0; _j < 8; ++_j) { \
                uint _pv = P[_g * 8 + _j]; \
                f32x2 _v; \
                _v.x = __uint_as_float(_pv << 16); \
                _v.y = __uint_as_float(_pv & 0xffff0000u); \
                float _w = W[_g * 8 + _j]; \
                acc2 += _v * (f32x2){_w, _w}; \
            } \
        } \
    } \
} while (0)

template<int NT>
__device__ __forceinline__ void fused_body(const uint* __restrict__ sup,
                                           const int2* __restrict__ rsp2,
                                           const uint* __restrict__ edges,
                                           const float* __restrict__ bias,
                                           const ushort* __restrict__ BT,
                                           int Nout,
                                           ushort* __restrict__ Cout) {
    __shared__ ushort a4_s[4][64 * 40];
    __shared__ int e_s[4][17];     // [0]=stream start; [i+1]=end of node i
    int tid = threadIdx.x;
    int wave = tid >> 6, lane = tid & 63;
    int row0 = blockIdx.x * 64;
    int nfirst = row0 + wave * 16;
    float bx = bias[2 * lane], by = bias[2 * lane + 1];
    int ks = lane >> 4;            // k-subtile of this lane's feature pair
    int kk = 2 * (lane & 15);      // k offset within the subtile

    if (lane < 16) {
        int nd = nfirst + lane; if (nd >= N_NODES) nd = N_NODES - 1;
        int2 t = rsp2[nd];
        e_s[wave][lane + 1] = t.y;
        if (lane == 0) e_s[wave][0] = t.x;
    }
    __syncthreads();
    int Q = e_s[wave][0], QE = e_s[wave][16];
    int cur = 0, e_cur = e_s[wave][1];
    f32x2 acc2 = (f32x2){0.f, 0.f};

    uint4 rA0, rA1, rA2, rA3, rB0, rB1, rB2, rB3;
    uint pa[16], pb[16];
    float wa[16], wb[16];
    int q = Q;
    // prologue (over-reads are clamped/guarded; stay inside workspace)
    LDREC(rA0, rA1, rA2, rA3, q);
    GATHER(pa, wa, rA0, rA1, rA2, rA3);
    LDREC(rB0, rB1, rB2, rB3, q + 16);
    while (q < QE) {
        GATHER(pb, wb, rB0, rB1, rB2, rB3);   // chunk q+16 gathers in flight
        LDREC(rA0, rA1, rA2, rA3, q + 32);    // chunk q+32 records in flight
        FMA_CHUNK(q, pa, wa);                 // consume chunk q
        q += 16;
        if (q >= QE) break;
        GATHER(pa, wa, rA0, rA1, rA2, rA3);
        LDREC(rB0, rB1, rB2, rB3, q + 32);
        FMA_CHUNK(q, pb, wb);
        q += 16;
    }
    while (cur < 16) FLUSH1();                // finalize remaining nodes
    __syncthreads();

    // GEMM: C[64 x Nout] = A(LDS) @ BT^T, K = 128.
    int lr = lane & 15, lk = (lane >> 4) * 8;
    f32x4 acc[4][NT];
    #pragma unroll
    for (int mt = 0; mt < 4; ++mt)
        #pragma unroll
        for (int nt = 0; nt < NT; ++nt) acc[mt][nt] = (f32x4){0.f, 0.f, 0.f, 0.f};
    #pragma unroll
    for (int ksi = 0; ksi < 4; ++ksi) {
        int k0 = ksi * 32;
        bf16x8 bfr[NT];
        #pragma unroll
        for (int nt = 0; nt < NT; ++nt)
            bfr[nt] = *(const bf16x8*)(BT +
                (size_t)((wave * NT + nt) * 16 + lr) * 128 + k0 + lk);
        #pragma unroll
        for (int mt = 0; mt < 4; ++mt) {
            bf16x8 afr = *(const bf16x8*)(&a4_s[ksi][(mt * 16 + lr) * 40 + lk]);
            #pragma unroll
            for (int nt = 0; nt < NT; ++nt)
                acc[mt][nt] = __builtin_amdgcn_mfma_f32_16x16x32_bf16(
                    afr, bfr[nt], acc[mt][nt], 0, 0, 0);
        }
    }
    int col0 = wave * NT * 16;
    #pragma unroll
    for (int mt = 0; mt < 4; ++mt) {
        int gr0 = row0 + mt * 16 + (lane >> 4) * 4;
        #pragma unroll
        for (int nt = 0; nt < NT; ++nt) {
            int gc = col0 + nt * 16 + lr;
            #pragma unroll
            for (int i = 0; i < 4; ++i) {
                int gr = gr0 + i;
                if (gr < N_NODES && gc < Nout)
                    Cout[(size_t)gr * Nout + gc] = f2bf(acc[mt][nt][i]);
            }
        }
    }
}

__global__ __launch_bounds__(256) void fused_ag2(const uint* __restrict__ sup,
                                                 const int2* __restrict__ rsp2,
                                                 const uint* __restrict__ edges,
                                                 const float* __restrict__ bias,
                                                 const ushort* __restrict__ BT,
                                                 ushort* __restrict__ Cout) {
    fused_body<2>(sup, rsp2, edges, bias, BT, 128, Cout);
}

__global__ __launch_bounds__(256) void fused_ag3(const uint* __restrict__ sup,
                                                 const int2* __restrict__ rsp2,
                                                 const uint* __restrict__ edges,
                                                 const float* __restrict__ bias,
                                                 const ushort* __restrict__ BT,
                                                 ushort* __restrict__ Cout) {
    fused_body<1>(sup, rsp2, edges, bias, BT, 40, Cout);
}

// ---------------------------------------------------------------------------
// Layer 3: bf16 F=40 segment-sum + bias + log_softmax fused -> out (fp32)
__global__ __launch_bounds__(256) void spmm40_lsm(const ushort* __restrict__ sup,
                                                  const int2* __restrict__ rsp2,
                                                  const uint* __restrict__ edges,
                                                  const float* __restrict__ bias,
                                                  float* __restrict__ out, int n) {
    int wid = blockIdx.x * 4 + (threadIdx.x >> 6);
    int lane = threadIdx.x & 63;
    if (wid >= n) return;
    int2 ke = rsp2[wid];
    int k = ke.x, e = ke.y;
    float acc = 0.f;
    int lf = (lane < 40) ? lane : 39;  // inactive lanes read lane 39 (no OOB)
    if (k < e) {
        const uint4* q4 = (const uint4*)(edges + k);
        uint4 qa = q4[0], qb = q4[1];
        for (; k < e; k += 8) {
            int kn = k + 8;
            int kc = (kn < e) ? kn : k;
            const uint4* n4 = (const uint4*)(edges + kc);
            uint4 na = n4[0], nb4 = n4[1];
            uint q[8] = {qa.x, qa.y, qa.z, qa.w, qb.x, qb.y, qb.z, qb.w};
            float p[8];
            #pragma unroll
            for (int j = 0; j < 8; ++j) {
                uint us = sup[(size_t)(q[j] & 0xffffu) * 40 + lf];
                p[j] = __uint_as_float(us << 16);
            }
            #pragma unroll
            for (int j = 0; j < 8; ++j)
                acc += p[j] * __uint_as_float(q[j] & 0xffff0000u);
            qa = na; qb = nb4;
        }
    }
    float v = (lane < 40) ? acc + bias[lane] : -INFINITY;
    float m = v;
    #pragma unroll
    for (int off = 32; off; off >>= 1) m = fmaxf(m, __shfl_xor(m, off, 64));
    float ex = (lane < 40) ? expf(v - m) : 0.f;
    float s = ex;
    #pragma unroll
    for (int off = 32; off; off >>= 1) s += __shfl_xor(s, off, 64);
    float ls = logf(s);
    if (lane < 40) out[(size_t)wid * 40 + lane] = v - m - ls;
}

// ---------------------------------------------------------------------------
extern "C" void kernel_launch(void* const* d_in, const int* in_sizes, int n_in,
                              void* d_out, int out_size, void* d_ws, size_t ws_size,
                              hipStream_t stream) {
    const float* x   = (const float*)d_in[0];
    const float* ew  = (const float*)d_in[1];
    const float* W1  = (const float*)d_in[2];
    const float* b1  = (const float*)d_in[3];
    const float* W2  = (const float*)d_in[4];
    const float* b2  = (const float*)d_in[5];
    const float* W3  = (const float*)d_in[6];
    const float* b3  = (const float*)d_in[7];
    const int* esrc  = (const int*)d_in[8];
    const int* edst  = (const int*)d_in[9];
    float* out = (float*)d_out;

    char* ws = (char*)d_ws;
    size_t off = 0;
    auto alloc = [&](size_t bytes) {
        size_t cur = off;
        off += (bytes + 255) & ~(size_t)255;
        return cur;
    };
    int* bucket_cnt = (int*)(ws + alloc(256 * sizeof(int)));
    int2* rsp2   = (int2*)(ws + alloc((size_t)N_NODES * sizeof(int2)));          // 400 KB
    uint* edges  = (uint*)(ws + alloc((size_t)NBUCK * BUCK_WIN * sizeof(uint))); // 4.6 MB
    int2* staging = (int2*)(ws + alloc((size_t)NBUCK * BUCK_CAP * sizeof(int2))); // 6.4 MB
    ushort* BT1  = (ushort*)(ws + alloc(128 * 256 * 2));
    ushort* BT2  = (ushort*)(ws + alloc(128 * 128 * 2));
    ushort* BT3  = (ushort*)(ws + alloc(64 * 128 * 2));
    char* Sreg   = ws + alloc((size_t)N_NODES * 128 * 2);       // 12.8 MB
    char* Hreg   = ws + alloc((size_t)N_NODES * 128 * 2);       // 12.8 MB
    (void)alloc((size_t)66000 * 128 * 2);   // clamp-gather slack past Hreg (16.9 MB)

    ushort* supA = (ushort*)Sreg;                  // gemm1 out
    ushort* supB = (ushort*)Hreg;                  // fused ag2 out
    ushort* sup3 = (ushort*)Sreg;                  // fused ag3 out (supA dead), 40/row

    hipMemsetAsync(bucket_cnt, 0, 256 * sizeof(int), stream);
    // K1: edge binning || weight conversion
    binA_cvtw<<<BINA_BLOCKS + CVTW_BLOCKS, 256, 0, stream>>>(
        esrc, edst, ew, bucket_cnt, staging, N_EDGES, W1, W2, W3, BT1, BT2, BT3);
    // K2: per-bucket scan+scatter (fixed windows) || GEMM1
    scan_gemm1<<<NBUCK + GEMM_BLOCKS, 256, 0, stream>>>(
        bucket_cnt, staging, rsp2, edges, x, BT1, supA);
    // K3: [agg1 + b1 + relu] -> GEMM x BT2 -> supB
    fused_ag2<<<GEMM_BLOCKS, 256, 0, stream>>>(
        (const uint*)supA, rsp2, edges, b1, BT2, supB);
    // K4: [agg2 + b2 + relu] -> GEMM x BT3 -> sup3 (40/row)
    fused_ag3<<<GEMM_BLOCKS, 256, 0, stream>>>(
        (const uint*)supB, rsp2, edges, b2, BT3, sup3);
    // K5: agg3 + b3 + log_softmax -> out
    spmm40_lsm<<<(N_NODES + 3) / 4, 256, 0, stream>>>(sup3, rsp2, edges, b3,
                                                      out, N_NODES);
}

// Round 7
// 215.382 us; speedup vs baseline: 6.5281x; 1.0038x over previous
//
#include <hip/hip_runtime.h>
#include <math.h>

#define N_NODES 50000
#define N_EDGES 600000
#define NFEAT   256
#define NHID    128
#define NCLASS  40
#define NBUCK 196            // bucket = dst >> 8 (256-node windows)
#define EPB_A 2048           // edges per phase-A block
#define BUCK_CAP 4096        // staging capacity per bucket (mean ~3062)
#define BUCK_WIN 5888        // fixed CSR window per bucket >= BUCK_CAP + 7*256 (mult of 8)
#define BINA_BLOCKS ((N_EDGES + EPB_A - 1) / EPB_A)   // 293
#define CVTW_BLOCKS 224                               // 57344 weight elems / 256
#define GEMM_BLOCKS ((N_NODES + 63) / 64)             // 782   (GEMM1 64-row tiles)
#define TILE_BLOCKS ((N_NODES + 31) / 32)             // 1563  (fused 32-row tiles)

typedef __attribute__((ext_vector_type(8))) short bf16x8;
typedef __attribute__((ext_vector_type(4))) float f32x4;
typedef __attribute__((ext_vector_type(2))) float f32x2;

__device__ inline ushort f2bf(float f) {   // RNE, finite inputs
    uint u = __float_as_uint(f);
    uint r = (u + 0x7fffu + ((u >> 16) & 1u)) >> 16;
    return (ushort)r;
}

// ---------------------------------------------------------------------------
// K1: blocks [0, BINA_BLOCKS) bin edges by 256-node bucket into fixed-capacity
// staging regions (record: uint = (bf16(w)<<16) | src; entry {rec, dst&255}).
// Blocks [BINA_BLOCKS, +CVTW_BLOCKS) convert the three weight matrices to
// transposed bf16.
__global__ __launch_bounds__(256) void binA_cvtw(const int* __restrict__ src,
                                                 const int* __restrict__ dst,
                                                 const float* __restrict__ w,
                                                 int* __restrict__ bucket_cnt,
                                                 int2* __restrict__ staging, int E,
                                                 const float* __restrict__ W1,
                                                 const float* __restrict__ W2,
                                                 const float* __restrict__ W3,
                                                 ushort* __restrict__ BT1,
                                                 ushort* __restrict__ BT2,
                                                 ushort* __restrict__ BT3) {
    int tid = threadIdx.x;
    if ((int)blockIdx.x >= BINA_BLOCKS) {
        int idx = ((int)blockIdx.x - BINA_BLOCKS) * 256 + tid;
        if (idx < 32768) {                       // BT1: 128x256 from W1[256x128]
            int nr = idx >> 8, k = idx & 255;
            BT1[idx] = f2bf(W1[(size_t)k * 128 + nr]);
        } else if (idx < 49152) {                // BT2: 128x128 from W2[128x128]
            int t = idx - 32768;
            int nr = t >> 7, k = t & 127;
            BT2[t] = f2bf(W2[(size_t)k * 128 + nr]);
        } else if (idx < 57344) {                // BT3: 64x128 from W3[128x40], zero-pad
            int t = idx - 49152;
            int nr = t >> 7, k = t & 127;
            BT3[t] = (nr < 40) ? f2bf(W3[(size_t)k * 40 + nr]) : (ushort)0;
        }
        return;
    }
    __shared__ int lh[NBUCK];
    for (int b = tid; b < NBUCK; b += 256) lh[b] = 0;
    __syncthreads();
    int base = blockIdx.x * EPB_A;
    int d[8];
    #pragma unroll
    for (int j = 0; j < 8; ++j) {
        int i = base + j * 256 + tid;
        d[j] = (i < E) ? dst[i] : -1;
        if (d[j] >= 0) atomicAdd(&lh[d[j] >> 8], 1);
    }
    __syncthreads();
    for (int b = tid; b < NBUCK; b += 256) {
        int c = lh[b];
        lh[b] = c ? (b * BUCK_CAP + atomicAdd(&bucket_cnt[b], c)) : 0;
    }
    __syncthreads();
    #pragma unroll
    for (int j = 0; j < 8; ++j) {
        int i = base + j * 256 + tid;
        if (d[j] >= 0) {
            int slot = atomicAdd(&lh[d[j] >> 8], 1);
            uint rec = ((uint)f2bf(w[i]) << 16) | (uint)src[i];
            staging[slot] = make_int2((int)rec, d[j] & 255);
        }
    }
}

// ---------------------------------------------------------------------------
// bf16 MFMA GEMM body (global-A variant, used for GEMM1 only; 64-row tiles).
template<int NT, bool AF32>
__device__ __forceinline__ void gemm_body(const void* __restrict__ Ain,
                                          const ushort* __restrict__ BT,
                                          int M, int K, int Nout,
                                          ushort* __restrict__ Cout, int row0) {
    __shared__ ushort a_s[64 * 40];
    __shared__ ushort b_s[64 * NT * 40];
    int tid = threadIdx.x;
    int wave = tid >> 6, lane = tid & 63;
    int lr = lane & 15, lk = (lane >> 4) * 8;
    f32x4 acc[4][NT];
    #pragma unroll
    for (int mt = 0; mt < 4; ++mt)
        #pragma unroll
        for (int nt = 0; nt < NT; ++nt) acc[mt][nt] = (f32x4){0.f, 0.f, 0.f, 0.f};

    for (int k0 = 0; k0 < K; k0 += 32) {
        {   // A tile: 64 rows x 32 k, 8 elems/thread
            int r = tid >> 2, c8 = (tid & 3) * 8;
            int gr = row0 + r; if (gr >= M) gr = M - 1;  // clamp, store-guarded
            if (AF32) {
                const float* Af = (const float*)Ain;
                float4 v0 = *(const float4*)(Af + (size_t)gr * K + k0 + c8);
                float4 v1 = *(const float4*)(Af + (size_t)gr * K + k0 + c8 + 4);
                ushort4 o0, o1;
                o0.x = f2bf(v0.x); o0.y = f2bf(v0.y); o0.z = f2bf(v0.z); o0.w = f2bf(v0.w);
                o1.x = f2bf(v1.x); o1.y = f2bf(v1.y); o1.z = f2bf(v1.z); o1.w = f2bf(v1.w);
                *(ushort4*)(a_s + r * 40 + c8) = o0;
                *(ushort4*)(a_s + r * 40 + c8 + 4) = o1;
            } else {
                const ushort* Ab = (const ushort*)Ain;
                float4 v = *(const float4*)(Ab + (size_t)gr * K + k0 + c8);
                *(float4*)(a_s + r * 40 + c8) = v;
            }
        }
        #pragma unroll
        for (int i = 0; i < NT; ++i) {  // BT tile: 64*NT rows x 32 k
            int idx = tid * NT + i;
            int r = idx >> 2, c8 = (idx & 3) * 8;
            float4 v = *(const float4*)(BT + (size_t)r * K + k0 + c8);
            *(float4*)(b_s + r * 40 + c8) = v;
        }
        __syncthreads();
        bf16x8 bfr[NT];
        #pragma unroll
        for (int nt = 0; nt < NT; ++nt)
            bfr[nt] = *(const bf16x8*)(b_s + ((wave * NT + nt) * 16 + lr) * 40 + lk);
        #pragma unroll
        for (int mt = 0; mt < 4; ++mt) {
            bf16x8 afr = *(const bf16x8*)(a_s + (mt * 16 + lr) * 40 + lk);
            #pragma unroll
            for (int nt = 0; nt < NT; ++nt)
                acc[mt][nt] = __builtin_amdgcn_mfma_f32_16x16x32_bf16(
                    afr, bfr[nt], acc[mt][nt], 0, 0, 0);
        }
        __syncthreads();
    }
    // C/D layout: col = lane&15, row = (lane>>4)*4 + i
    int col0 = wave * NT * 16;
    #pragma unroll
    for (int mt = 0; mt < 4; ++mt) {
        int gr0 = row0 + mt * 16 + (lane >> 4) * 4;
        #pragma unroll
        for (int nt = 0; nt < NT; ++nt) {
            int gc = col0 + nt * 16 + lr;
            #pragma unroll
            for (int i = 0; i < 4; ++i) {
                int gr = gr0 + i;
                if (gr < M && gc < Nout)
                    Cout[(size_t)gr * Nout + gc] = f2bf(acc[mt][nt][i]);
            }
        }
    }
}

// ---------------------------------------------------------------------------
// K2: blocks [0, NBUCK) do self-contained per-bucket scan+scatter into FIXED
// windows (gaps never read -> no global prefix). Blocks [NBUCK, +782) run
// GEMM1 (x fp32 -> supA bf16), overlapping the CSR tail.
__global__ __launch_bounds__(256) void scan_gemm1(const int* __restrict__ bucket_cnt,
                                                  const int2* __restrict__ staging,
                                                  int2* __restrict__ rsp2,
                                                  uint* __restrict__ edges,
                                                  const float* __restrict__ x,
                                                  const ushort* __restrict__ BT1,
                                                  ushort* __restrict__ supA) {
    if ((int)blockIdx.x >= NBUCK) {
        gemm_body<2, true>(x, BT1, N_NODES, 256, 128, supA,
                           ((int)blockIdx.x - NBUCK) * 64);
        return;
    }
    __shared__ int hist[256];
    __shared__ int buf[256];
    __shared__ int lcur[256];
    int tid = threadIdx.x;
    hist[tid] = 0;
    __syncthreads();
    int b = blockIdx.x;
    int c = bucket_cnt[b];
    const int2* st = staging + (size_t)b * BUCK_CAP;
    for (int p = tid; p < c; p += 256) atomicAdd(&hist[st[p].y], 1);
    __syncthreads();
    int v = (hist[tid] + 7) & ~7;   // pad per-node count to multiple of 8
    buf[tid] = v;
    __syncthreads();
    #pragma unroll
    for (int off = 1; off < 256; off <<= 1) {
        int t = (tid >= off) ? buf[tid - off] : 0;
        __syncthreads();
        buf[tid] += t;
        __syncthreads();
    }
    int bb = b * BUCK_WIN;
    int ex = buf[tid] - v + bb;
    int i = b * 256 + tid;
    if (i < N_NODES) rsp2[i] = make_int2(ex, ex + v);
    lcur[tid] = ex;
    __syncthreads();
    int e0 = bb + buf[255];
    for (int p = bb + tid; p < e0; p += 256) edges[p] = 0;   // covers padding
    __syncthreads();
    for (int p = tid; p < c; p += 256) {
        int2 r = st[p];
        int slot = atomicAdd(&lcur[r.y], 1);
        edges[slot] = (uint)r.x;
    }
}

// ---------------------------------------------------------------------------
// Flattened-stream engine (proven round 6): a wave's nodes are contiguous in
// the padded CSR; process ONE edge stream in 16-edge ping-pong chunks with an
// advancing flush pointer at node boundaries (all control wave-uniform).
// ROUND-7: 32-row tiles (8 nodes/wave, TILE_BLOCKS grid) -> 2x blocks/CU of
// TLP for the latency-bound gather phase; same engine applied to layer 3.

#define LDREC(Ra, Rb, Rc, Rd, POS) do { \
    const uint4* _p = (const uint4*)(edges + (POS)); \
    Ra = _p[0]; Rb = _p[1]; Rc = _p[2]; Rd = _p[3]; \
} while (0)

#define GATHER(P, W, Ra, Rb, Rc, Rd) do { \
    uint _r[16] = {Ra.x, Ra.y, Ra.z, Ra.w, Rb.x, Rb.y, Rb.z, Rb.w, \
                   Rc.x, Rc.y, Rc.z, Rc.w, Rd.x, Rd.y, Rd.z, Rd.w}; \
    _Pragma("unroll") \
    for (int _j = 0; _j < 16; ++_j) { \
        uint _idx = _r[_j] & 0xffffu; \
        if (_idx >= N_NODES) _idx = N_NODES - 1;  /* garbage-tail safety */ \
        P[_j] = sup[(size_t)_idx * 64 + lane]; \
        W[_j] = __uint_as_float(_r[_j] & 0xffff0000u); \
    } \
} while (0)

#define FLUSH_A() do { \
    uint _pk = ((uint)f2bf(fmaxf(acc2.y + by, 0.f)) << 16) \
             |  (uint)f2bf(fmaxf(acc2.x + bx, 0.f)); \
    *(uint*)(&a4_s[ks][(wave * 8 + cur) * 40 + kk]) = _pk; \
    acc2 = (f32x2){0.f, 0.f}; \
    ++cur; \
    e_cur = (cur < 8) ? e_s[wave][cur + 1] : 0x7fffffff; \
} while (0)

#define FMA_CHUNK_A(QB, P, W) do { \
    _Pragma("unroll") \
    for (int _g = 0; _g < 2; ++_g) { \
        int _qg = (QB) + _g * 8; \
        while (cur < 8 && _qg >= e_cur) FLUSH_A(); \
        if (_qg < QE) { \
            _Pragma("unroll") \
            for (int _j = 0; _j < 8; ++_j) { \
                uint _pv = P[_g * 8 + _j]; \
                f32x2 _v; \
                _v.x = __uint_as_float(_pv << 16); \
                _v.y = __uint_as_float(_pv & 0xffff0000u); \
                float _w = W[_g * 8 + _j]; \
                acc2 += _v * (f32x2){_w, _w}; \
            } \
        } \
    } \
} while (0)

template<int NT>
__device__ __forceinline__ void fused_body(const uint* __restrict__ sup,
                                           const int2* __restrict__ rsp2,
                                           const uint* __restrict__ edges,
                                           const float* __restrict__ bias,
                                           const ushort* __restrict__ BT,
                                           int Nout,
                                           ushort* __restrict__ Cout) {
    __shared__ ushort a4_s[4][32 * 40];
    __shared__ int e_s[4][9];      // [0]=stream start; [i+1]=end of node i
    int tid = threadIdx.x;
    int wave = tid >> 6, lane = tid & 63;
    int row0 = blockIdx.x * 32;
    int nfirst = row0 + wave * 8;
    float bx = bias[2 * lane], by = bias[2 * lane + 1];
    int ks = lane >> 4;            // k-subtile of this lane's feature pair
    int kk = 2 * (lane & 15);      // k offset within the subtile

    if (lane < 8) {
        int nd = nfirst + lane; if (nd >= N_NODES) nd = N_NODES - 1;
        int2 t = rsp2[nd];
        e_s[wave][lane + 1] = t.y;
        if (lane == 0) e_s[wave][0] = t.x;
    }
    __syncthreads();
    int Q = e_s[wave][0], QE = e_s[wave][8];
    int cur = 0, e_cur = e_s[wave][1];
    f32x2 acc2 = (f32x2){0.f, 0.f};

    uint4 rA0, rA1, rA2, rA3, rB0, rB1, rB2, rB3;
    uint pa[16], pb[16];
    float wa[16], wb[16];
    int q = Q;
    // prologue (over-reads are clamped/guarded; stay inside workspace)
    LDREC(rA0, rA1, rA2, rA3, q);
    GATHER(pa, wa, rA0, rA1, rA2, rA3);
    LDREC(rB0, rB1, rB2, rB3, q + 16);
    while (q < QE) {
        GATHER(pb, wb, rB0, rB1, rB2, rB3);   // chunk q+16 gathers in flight
        LDREC(rA0, rA1, rA2, rA3, q + 32);    // chunk q+32 records in flight
        FMA_CHUNK_A(q, pa, wa);               // consume chunk q
        q += 16;
        if (q >= QE) break;
        GATHER(pa, wa, rA0, rA1, rA2, rA3);
        LDREC(rB0, rB1, rB2, rB3, q + 32);
        FMA_CHUNK_A(q, pb, wb);
        q += 16;
    }
    while (cur < 8) FLUSH_A();                // finalize remaining nodes
    __syncthreads();

    // GEMM: C[32 x Nout] = A(LDS) @ BT^T, K = 128.
    int lr = lane & 15, lk = (lane >> 4) * 8;
    f32x4 acc[2][NT];
    #pragma unroll
    for (int mt = 0; mt < 2; ++mt)
        #pragma unroll
        for (int nt = 0; nt < NT; ++nt) acc[mt][nt] = (f32x4){0.f, 0.f, 0.f, 0.f};
    #pragma unroll
    for (int ksi = 0; ksi < 4; ++ksi) {
        int k0 = ksi * 32;
        bf16x8 bfr[NT];
        #pragma unroll
        for (int nt = 0; nt < NT; ++nt)
            bfr[nt] = *(const bf16x8*)(BT +
                (size_t)((wave * NT + nt) * 16 + lr) * 128 + k0 + lk);
        #pragma unroll
        for (int mt = 0; mt < 2; ++mt) {
            bf16x8 afr = *(const bf16x8*)(&a4_s[ksi][(mt * 16 + lr) * 40 + lk]);
            #pragma unroll
            for (int nt = 0; nt < NT; ++nt)
                acc[mt][nt] = __builtin_amdgcn_mfma_f32_16x16x32_bf16(
                    afr, bfr[nt], acc[mt][nt], 0, 0, 0);
        }
    }
    int col0 = wave * NT * 16;
    #pragma unroll
    for (int mt = 0; mt < 2; ++mt) {
        int gr0 = row0 + mt * 16 + (lane >> 4) * 4;
        #pragma unroll
        for (int nt = 0; nt < NT; ++nt) {
            int gc = col0 + nt * 16 + lr;
            #pragma unroll
            for (int i = 0; i < 4; ++i) {
                int gr = gr0 + i;
                if (gr < N_NODES && gc < Nout)
                    Cout[(size_t)gr * Nout + gc] = f2bf(acc[mt][nt][i]);
            }
        }
    }
}

__global__ __launch_bounds__(256) void fused_ag2(const uint* __restrict__ sup,
                                                 const int2* __restrict__ rsp2,
                                                 const uint* __restrict__ edges,
                                                 const float* __restrict__ bias,
                                                 const ushort* __restrict__ BT,
                                                 ushort* __restrict__ Cout) {
    fused_body<2>(sup, rsp2, edges, bias, BT, 128, Cout);
}

__global__ __launch_bounds__(256) void fused_ag3(const uint* __restrict__ sup,
                                                 const int2* __restrict__ rsp2,
                                                 const uint* __restrict__ edges,
                                                 const float* __restrict__ bias,
                                                 const ushort* __restrict__ BT,
                                                 ushort* __restrict__ Cout) {
    fused_body<1>(sup, rsp2, edges, bias, BT, 64, Cout);   // F=64, cols 40..63 zero
}

// ---------------------------------------------------------------------------
// Layer 3 aggregation + bias + log_softmax, flattened-stream (8 nodes/wave).
// sup3 is F=64 natural layout (cols 40..63 zero); lane owns one feature.
// Flush at node boundary = wave-uniform lsm reduction + scattered out write.

#define GATHER_U16(P, W, Ra, Rb, Rc, Rd) do { \
    uint _r[16] = {Ra.x, Ra.y, Ra.z, Ra.w, Rb.x, Rb.y, Rb.z, Rb.w, \
                   Rc.x, Rc.y, Rc.z, Rc.w, Rd.x, Rd.y, Rd.z, Rd.w}; \
    _Pragma("unroll") \
    for (int _j = 0; _j < 16; ++_j) { \
        uint _idx = _r[_j] & 0xffffu; \
        if (_idx >= N_NODES) _idx = N_NODES - 1; \
        P[_j] = __uint_as_float((uint)sup[(size_t)_idx * 64 + lane] << 16); \
        W[_j] = __uint_as_float(_r[_j] & 0xffff0000u); \
    } \
} while (0)

#define FLUSH_L() do { \
    int _node = nfirst + cur; \
    float _v = (lane < 40) ? acc1 + bl : -INFINITY; \
    float _m = _v; \
    _Pragma("unroll") \
    for (int _o = 32; _o; _o >>= 1) _m = fmaxf(_m, __shfl_xor(_m, _o, 64)); \
    float _ex = (lane < 40) ? expf(_v - _m) : 0.f; \
    float _s = _ex; \
    _Pragma("unroll") \
    for (int _o = 32; _o; _o >>= 1) _s += __shfl_xor(_s, _o, 64); \
    float _ls = logf(_s); \
    if (lane < 40 && _node < N_NODES) \
        out[(size_t)_node * 40 + lane] = _v - _m - _ls; \
    acc1 = 0.f; \
    ++cur; \
    e_cur = (cur < 8) ? e_s[wave][cur + 1] : 0x7fffffff; \
} while (0)

#define FMA_CHUNK_L(QB, P, W) do { \
    _Pragma("unroll") \
    for (int _g = 0; _g < 2; ++_g) { \
        int _qg = (QB) + _g * 8; \
        while (cur < 8 && _qg >= e_cur) FLUSH_L(); \
        if (_qg < QE) { \
            _Pragma("unroll") \
            for (int _j = 0; _j < 8; ++_j) \
                acc1 += P[_g * 8 + _j] * W[_g * 8 + _j]; \
        } \
    } \
} while (0)

__global__ __launch_bounds__(256) void agg_lsm(const ushort* __restrict__ sup,
                                               const int2* __restrict__ rsp2,
                                               const uint* __restrict__ edges,
                                               const float* __restrict__ bias,
                                               float* __restrict__ out) {
    __shared__ int e_s[4][9];
    int tid = threadIdx.x;
    int wave = tid >> 6, lane = tid & 63;
    int nfirst = blockIdx.x * 32 + wave * 8;
    float bl = (lane < 40) ? bias[lane] : 0.f;
    if (lane < 8) {
        int nd = nfirst + lane; if (nd >= N_NODES) nd = N_NODES - 1;
        int2 t = rsp2[nd];
        e_s[wave][lane + 1] = t.y;
        if (lane == 0) e_s[wave][0] = t.x;
    }
    __syncthreads();
    int Q = e_s[wave][0], QE = e_s[wave][8];
    int cur = 0, e_cur = e_s[wave][1];
    float acc1 = 0.f;

    uint4 rA0, rA1, rA2, rA3, rB0, rB1, rB2, rB3;
    float pa[16], pb[16];
    float wa[16], wb[16];
    int q = Q;
    LDREC(rA0, rA1, rA2, rA3, q);
    GATHER_U16(pa, wa, rA0, rA1, rA2, rA3);
    LDREC(rB0, rB1, rB2, rB3, q + 16);
    while (q < QE) {
        GATHER_U16(pb, wb, rB0, rB1, rB2, rB3);
        LDREC(rA0, rA1, rA2, rA3, q + 32);
        FMA_CHUNK_L(q, pa, wa);
        q += 16;
        if (q >= QE) break;
        GATHER_U16(pa, wa, rA0, rA1, rA2, rA3);
        LDREC(rB0, rB1, rB2, rB3, q + 32);
        FMA_CHUNK_L(q, pb, wb);
        q += 16;
    }
    while (cur < 8) FLUSH_L();
}

// ---------------------------------------------------------------------------
extern "C" void kernel_launch(void* const* d_in, const int* in_sizes, int n_in,
                              void* d_out, int out_size, void* d_ws, size_t ws_size,
                              hipStream_t stream) {
    const float* x   = (const float*)d_in[0];
    const float* ew  = (const float*)d_in[1];
    const float* W1  = (const float*)d_in[2];
    const float* b1  = (const float*)d_in[3];
    const float* W2  = (const float*)d_in[4];
    const float* b2  = (const float*)d_in[5];
    const float* W3  = (const float*)d_in[6];
    const float* b3  = (const float*)d_in[7];
    const int* esrc  = (const int*)d_in[8];
    const int* edst  = (const int*)d_in[9];
    float* out = (float*)d_out;

    char* ws = (char*)d_ws;
    size_t off = 0;
    auto alloc = [&](size_t bytes) {
        size_t cur = off;
        off += (bytes + 255) & ~(size_t)255;
        return cur;
    };
    int* bucket_cnt = (int*)(ws + alloc(256 * sizeof(int)));
    int2* rsp2   = (int2*)(ws + alloc((size_t)N_NODES * sizeof(int2)));          // 400 KB
    uint* edges  = (uint*)(ws + alloc((size_t)NBUCK * BUCK_WIN * sizeof(uint))); // 4.6 MB
    int2* staging = (int2*)(ws + alloc((size_t)NBUCK * BUCK_CAP * sizeof(int2))); // 6.4 MB
    ushort* BT1  = (ushort*)(ws + alloc(128 * 256 * 2));
    ushort* BT2  = (ushort*)(ws + alloc(128 * 128 * 2));
    ushort* BT3  = (ushort*)(ws + alloc(64 * 128 * 2));
    char* Sreg   = ws + alloc((size_t)N_NODES * 128 * 2);       // 12.8 MB
    char* Hreg   = ws + alloc((size_t)N_NODES * 128 * 2);       // 12.8 MB
    (void)alloc((size_t)66000 * 128 * 2);   // clamp-gather slack past Hreg

    ushort* supA = (ushort*)Sreg;                  // gemm1 out
    ushort* supB = (ushort*)Hreg;                  // fused ag2 out
    ushort* sup3 = (ushort*)Sreg;                  // fused ag3 out (supA dead), F=64

    hipMemsetAsync(bucket_cnt, 0, 256 * sizeof(int), stream);
    // K1: edge binning || weight conversion
    binA_cvtw<<<BINA_BLOCKS + CVTW_BLOCKS, 256, 0, stream>>>(
        esrc, edst, ew, bucket_cnt, staging, N_EDGES, W1, W2, W3, BT1, BT2, BT3);
    // K2: per-bucket scan+scatter (fixed windows) || GEMM1
    scan_gemm1<<<NBUCK + GEMM_BLOCKS, 256, 0, stream>>>(
        bucket_cnt, staging, rsp2, edges, x, BT1, supA);
    // K3: [agg1 + b1 + relu] -> GEMM x BT2 -> supB
    fused_ag2<<<TILE_BLOCKS, 256, 0, stream>>>(
        (const uint*)supA, rsp2, edges, b1, BT2, supB);
    // K4: [agg2 + b2 + relu] -> GEMM x BT3 -> sup3 (F=64, cols 40..63 zero)
    fused_ag3<<<TILE_BLOCKS, 256, 0, stream>>>(
        (const uint*)supB, rsp2, edges, b2, BT3, sup3);
    // K5: agg3 + b3 + log_softmax -> out (flattened stream)
    agg_lsm<<<TILE_BLOCKS, 256, 0, stream>>>(sup3, rsp2, edges, b3, out);
}

// Round 8
// 210.156 us; speedup vs baseline: 6.6904x; 1.0249x over previous
//
#include <hip/hip_runtime.h>
#include <math.h>

#define N_NODES 50000
#define N_EDGES 600000
#define NFEAT   256
#define NHID    128
#define NCLASS  40
#define NBUCK 196            // bucket = dst >> 8 (256-node windows)
#define EPB_A 2048           // edges per phase-A block
#define BUCK_CAP 4096        // staging capacity per bucket (mean ~3062)
#define BUCK_WIN 5888        // fixed CSR window per bucket >= BUCK_CAP + 7*256 (mult of 8)
#define BINA_BLOCKS ((N_EDGES + EPB_A - 1) / EPB_A)   // 293
#define CVTW_BLOCKS 224                               // 57344 weight elems / 256
#define GEMM_BLOCKS ((N_NODES + 63) / 64)             // 782   (GEMM1 64-row tiles)
#define TILE_BLOCKS ((N_NODES + 31) / 32)             // 1563  (fused 32-row tiles)

typedef __attribute__((ext_vector_type(8))) short bf16x8;
typedef __attribute__((ext_vector_type(4))) float f32x4;
typedef __attribute__((ext_vector_type(2))) float f32x2;

__device__ inline ushort f2bf(float f) {   // RNE, finite inputs
    uint u = __float_as_uint(f);
    uint r = (u + 0x7fffu + ((u >> 16) & 1u)) >> 16;
    return (ushort)r;
}

// ---------------------------------------------------------------------------
// K1: blocks [0, BINA_BLOCKS) bin edges by 256-node bucket into fixed-capacity
// staging regions (record: uint = (bf16(w)<<16) | src; entry {rec, dst&255}).
// Blocks [BINA_BLOCKS, +CVTW_BLOCKS) convert the three weight matrices to
// transposed bf16.
__global__ __launch_bounds__(256) void binA_cvtw(const int* __restrict__ src,
                                                 const int* __restrict__ dst,
                                                 const float* __restrict__ w,
                                                 int* __restrict__ bucket_cnt,
                                                 int2* __restrict__ staging, int E,
                                                 const float* __restrict__ W1,
                                                 const float* __restrict__ W2,
                                                 const float* __restrict__ W3,
                                                 ushort* __restrict__ BT1,
                                                 ushort* __restrict__ BT2,
                                                 ushort* __restrict__ BT3) {
    int tid = threadIdx.x;
    if ((int)blockIdx.x >= BINA_BLOCKS) {
        int idx = ((int)blockIdx.x - BINA_BLOCKS) * 256 + tid;
        if (idx < 32768) {                       // BT1: 128x256 from W1[256x128]
            int nr = idx >> 8, k = idx & 255;
            BT1[idx] = f2bf(W1[(size_t)k * 128 + nr]);
        } else if (idx < 49152) {                // BT2: 128x128 from W2[128x128]
            int t = idx - 32768;
            int nr = t >> 7, k = t & 127;
            BT2[t] = f2bf(W2[(size_t)k * 128 + nr]);
        } else if (idx < 57344) {                // BT3: 64x128 from W3[128x40], zero-pad
            int t = idx - 49152;
            int nr = t >> 7, k = t & 127;
            BT3[t] = (nr < 40) ? f2bf(W3[(size_t)k * 40 + nr]) : (ushort)0;
        }
        return;
    }
    __shared__ int lh[NBUCK];
    for (int b = tid; b < NBUCK; b += 256) lh[b] = 0;
    __syncthreads();
    int base = blockIdx.x * EPB_A;
    int d[8];
    #pragma unroll
    for (int j = 0; j < 8; ++j) {
        int i = base + j * 256 + tid;
        d[j] = (i < E) ? dst[i] : -1;
        if (d[j] >= 0) atomicAdd(&lh[d[j] >> 8], 1);
    }
    __syncthreads();
    for (int b = tid; b < NBUCK; b += 256) {
        int c = lh[b];
        lh[b] = c ? (b * BUCK_CAP + atomicAdd(&bucket_cnt[b], c)) : 0;
    }
    __syncthreads();
    #pragma unroll
    for (int j = 0; j < 8; ++j) {
        int i = base + j * 256 + tid;
        if (d[j] >= 0) {
            int slot = atomicAdd(&lh[d[j] >> 8], 1);
            uint rec = ((uint)f2bf(w[i]) << 16) | (uint)src[i];
            staging[slot] = make_int2((int)rec, d[j] & 255);
        }
    }
}

// ---------------------------------------------------------------------------
// bf16 MFMA GEMM body (global-A variant, used for GEMM1 only; 64-row tiles).
template<int NT, bool AF32>
__device__ __forceinline__ void gemm_body(const void* __restrict__ Ain,
                                          const ushort* __restrict__ BT,
                                          int M, int K, int Nout,
                                          ushort* __restrict__ Cout, int row0) {
    __shared__ ushort a_s[64 * 40];
    __shared__ ushort b_s[64 * NT * 40];
    int tid = threadIdx.x;
    int wave = tid >> 6, lane = tid & 63;
    int lr = lane & 15, lk = (lane >> 4) * 8;
    f32x4 acc[4][NT];
    #pragma unroll
    for (int mt = 0; mt < 4; ++mt)
        #pragma unroll
        for (int nt = 0; nt < NT; ++nt) acc[mt][nt] = (f32x4){0.f, 0.f, 0.f, 0.f};

    for (int k0 = 0; k0 < K; k0 += 32) {
        {   // A tile: 64 rows x 32 k, 8 elems/thread
            int r = tid >> 2, c8 = (tid & 3) * 8;
            int gr = row0 + r; if (gr >= M) gr = M - 1;  // clamp, store-guarded
            if (AF32) {
                const float* Af = (const float*)Ain;
                float4 v0 = *(const float4*)(Af + (size_t)gr * K + k0 + c8);
                float4 v1 = *(const float4*)(Af + (size_t)gr * K + k0 + c8 + 4);
                ushort4 o0, o1;
                o0.x = f2bf(v0.x); o0.y = f2bf(v0.y); o0.z = f2bf(v0.z); o0.w = f2bf(v0.w);
                o1.x = f2bf(v1.x); o1.y = f2bf(v1.y); o1.z = f2bf(v1.z); o1.w = f2bf(v1.w);
                *(ushort4*)(a_s + r * 40 + c8) = o0;
                *(ushort4*)(a_s + r * 40 + c8 + 4) = o1;
            } else {
                const ushort* Ab = (const ushort*)Ain;
                float4 v = *(const float4*)(Ab + (size_t)gr * K + k0 + c8);
                *(float4*)(a_s + r * 40 + c8) = v;
            }
        }
        #pragma unroll
        for (int i = 0; i < NT; ++i) {  // BT tile: 64*NT rows x 32 k
            int idx = tid * NT + i;
            int r = idx >> 2, c8 = (idx & 3) * 8;
            float4 v = *(const float4*)(BT + (size_t)r * K + k0 + c8);
            *(float4*)(b_s + r * 40 + c8) = v;
        }
        __syncthreads();
        bf16x8 bfr[NT];
        #pragma unroll
        for (int nt = 0; nt < NT; ++nt)
            bfr[nt] = *(const bf16x8*)(b_s + ((wave * NT + nt) * 16 + lr) * 40 + lk);
        #pragma unroll
        for (int mt = 0; mt < 4; ++mt) {
            bf16x8 afr = *(const bf16x8*)(a_s + (mt * 16 + lr) * 40 + lk);
            #pragma unroll
            for (int nt = 0; nt < NT; ++nt)
                acc[mt][nt] = __builtin_amdgcn_mfma_f32_16x16x32_bf16(
                    afr, bfr[nt], acc[mt][nt], 0, 0, 0);
        }
        __syncthreads();
    }
    // C/D layout: col = lane&15, row = (lane>>4)*4 + i
    int col0 = wave * NT * 16;
    #pragma unroll
    for (int mt = 0; mt < 4; ++mt) {
        int gr0 = row0 + mt * 16 + (lane >> 4) * 4;
        #pragma unroll
        for (int nt = 0; nt < NT; ++nt) {
            int gc = col0 + nt * 16 + lr;
            #pragma unroll
            for (int i = 0; i < 4; ++i) {
                int gr = gr0 + i;
                if (gr < M && gc < Nout)
                    Cout[(size_t)gr * Nout + gc] = f2bf(acc[mt][nt][i]);
            }
        }
    }
}

// ---------------------------------------------------------------------------
// K2: blocks [0, NBUCK) do self-contained per-bucket scan+scatter into FIXED
// windows (gaps never read -> no global prefix). Blocks [NBUCK, +782) run
// GEMM1 (x fp32 -> supA bf16), overlapping the CSR tail.
__global__ __launch_bounds__(256) void scan_gemm1(const int* __restrict__ bucket_cnt,
                                                  const int2* __restrict__ staging,
                                                  int2* __restrict__ rsp2,
                                                  uint* __restrict__ edges,
                                                  const float* __restrict__ x,
                                                  const ushort* __restrict__ BT1,
                                                  ushort* __restrict__ supA) {
    if ((int)blockIdx.x >= NBUCK) {
        gemm_body<2, true>(x, BT1, N_NODES, 256, 128, supA,
                           ((int)blockIdx.x - NBUCK) * 64);
        return;
    }
    __shared__ int hist[256];
    __shared__ int buf[256];
    __shared__ int lcur[256];
    int tid = threadIdx.x;
    hist[tid] = 0;
    __syncthreads();
    int b = blockIdx.x;
    int c = bucket_cnt[b];
    const int2* st = staging + (size_t)b * BUCK_CAP;
    for (int p = tid; p < c; p += 256) atomicAdd(&hist[st[p].y], 1);
    __syncthreads();
    int v = (hist[tid] + 7) & ~7;   // pad per-node count to multiple of 8
    buf[tid] = v;
    __syncthreads();
    #pragma unroll
    for (int off = 1; off < 256; off <<= 1) {
        int t = (tid >= off) ? buf[tid - off] : 0;
        __syncthreads();
        buf[tid] += t;
        __syncthreads();
    }
    int bb = b * BUCK_WIN;
    int ex = buf[tid] - v + bb;
    int i = b * 256 + tid;
    if (i < N_NODES) rsp2[i] = make_int2(ex, ex + v);
    lcur[tid] = ex;
    __syncthreads();
    int e0 = bb + buf[255];
    for (int p = bb + tid; p < e0; p += 256) edges[p] = 0;   // covers padding
    __syncthreads();
    for (int p = tid; p < c; p += 256) {
        int2 r = st[p];
        int slot = atomicAdd(&lcur[r.y], 1);
        edges[slot] = (uint)r.x;
    }
}

// ---------------------------------------------------------------------------
// Flattened-stream engine, ROUND-8: scalarized record path.
// Records are wave-uniform -> load them via readfirstlane'd base so they live
// in SGPRs (s_load), row index/clamp/base go SALU, and the gather becomes
// global_load_dword with SGPR base + shared lane-offset VGPR. Weights are
// extracted from the SGPR records at FMA time (no w arrays). 3 record
// buffers (q, q+16, q+32) rotate through a 6-phase unrolled loop; only
// pa/pb value arrays (32 VGPRs) remain vector-sized.

#define LDREC_S(R, POS) do { \
    int _ub = __builtin_amdgcn_readfirstlane(POS); \
    _Pragma("unroll") \
    for (int _i = 0; _i < 16; ++_i) R[_i] = edges[_ub + _i]; \
} while (0)

#define GATHER_S(P, R) do { \
    _Pragma("unroll") \
    for (int _j = 0; _j < 16; ++_j) { \
        uint _idx = R[_j] & 0xffffu; \
        _idx = (_idx < N_NODES) ? _idx : (N_NODES - 1);  /* SALU clamp */ \
        P[_j] = sup[(size_t)_idx * 64 + lane]; \
    } \
} while (0)

#define FLUSH_A() do { \
    uint _pk = ((uint)f2bf(fmaxf(acc2.y + by, 0.f)) << 16) \
             |  (uint)f2bf(fmaxf(acc2.x + bx, 0.f)); \
    *(uint*)(&a4_s[ks][(wave * 8 + cur) * 40 + kk]) = _pk; \
    acc2 = (f32x2){0.f, 0.f}; \
    ++cur; \
    e_cur = (cur < 8) ? e_s[wave][cur + 1] : 0x7fffffff; \
} while (0)

#define FMA_A(QB, P, R) do { \
    _Pragma("unroll") \
    for (int _g = 0; _g < 2; ++_g) { \
        int _qg = (QB) + _g * 8; \
        while (cur < 8 && _qg >= e_cur) FLUSH_A(); \
        if (_qg < QE) { \
            _Pragma("unroll") \
            for (int _j = 0; _j < 8; ++_j) { \
                uint _pv = P[_g * 8 + _j]; \
                float _w = __uint_as_float(R[_g * 8 + _j] & 0xffff0000u); \
                f32x2 _v; \
                _v.x = __uint_as_float(_pv << 16); \
                _v.y = __uint_as_float(_pv & 0xffff0000u); \
                acc2 += _v * (f32x2){_w, _w}; \
            } \
        } \
    } \
} while (0)

template<int NT>
__device__ __forceinline__ void fused_body(const uint* __restrict__ sup,
                                           const int2* __restrict__ rsp2,
                                           const uint* __restrict__ edges,
                                           const float* __restrict__ bias,
                                           const ushort* __restrict__ BT,
                                           int Nout,
                                           ushort* __restrict__ Cout) {
    __shared__ ushort a4_s[4][32 * 40];
    __shared__ int e_s[4][9];      // [0]=stream start; [i+1]=end of node i
    int tid = threadIdx.x;
    int wave = tid >> 6, lane = tid & 63;
    int row0 = blockIdx.x * 32;
    int nfirst = row0 + wave * 8;
    float bx = bias[2 * lane], by = bias[2 * lane + 1];
    int ks = lane >> 4;            // k-subtile of this lane's feature pair
    int kk = 2 * (lane & 15);      // k offset within the subtile

    if (lane < 8) {
        int nd = nfirst + lane; if (nd >= N_NODES) nd = N_NODES - 1;
        int2 t = rsp2[nd];
        e_s[wave][lane + 1] = t.y;
        if (lane == 0) e_s[wave][0] = t.x;
    }
    __syncthreads();
    int Q = e_s[wave][0], QE = e_s[wave][8];
    int cur = 0, e_cur = e_s[wave][1];
    f32x2 acc2 = (f32x2){0.f, 0.f};

    uint ra[16], rb[16], rc[16];   // uniform records -> SGPR candidates
    uint pa[16], pb[16];
    int q = Q;
    // prologue (over-reads clamped/guarded; stay inside workspace)
    LDREC_S(ra, q);
    GATHER_S(pa, ra);
    LDREC_S(rb, q + 16);
    while (q < QE) {
        // 6-phase rotation: chunk i uses record buf i%3, value buf i%2
        GATHER_S(pb, rb); LDREC_S(rc, q + 32); FMA_A(q, pa, ra);
        q += 16; if (q >= QE) break;
        GATHER_S(pa, rc); LDREC_S(ra, q + 32); FMA_A(q, pb, rb);
        q += 16; if (q >= QE) break;
        GATHER_S(pb, ra); LDREC_S(rb, q + 32); FMA_A(q, pa, rc);
        q += 16; if (q >= QE) break;
        GATHER_S(pa, rb); LDREC_S(rc, q + 32); FMA_A(q, pb, ra);
        q += 16; if (q >= QE) break;
        GATHER_S(pb, rc); LDREC_S(ra, q + 32); FMA_A(q, pa, rb);
        q += 16; if (q >= QE) break;
        GATHER_S(pa, ra); LDREC_S(rb, q + 32); FMA_A(q, pb, rc);
        q += 16;
    }
    while (cur < 8) FLUSH_A();                // finalize remaining nodes
    __syncthreads();

    // GEMM: C[32 x Nout] = A(LDS) @ BT^T, K = 128.
    int lr = lane & 15, lk = (lane >> 4) * 8;
    f32x4 acc[2][NT];
    #pragma unroll
    for (int mt = 0; mt < 2; ++mt)
        #pragma unroll
        for (int nt = 0; nt < NT; ++nt) acc[mt][nt] = (f32x4){0.f, 0.f, 0.f, 0.f};
    #pragma unroll
    for (int ksi = 0; ksi < 4; ++ksi) {
        int k0 = ksi * 32;
        bf16x8 bfr[NT];
        #pragma unroll
        for (int nt = 0; nt < NT; ++nt)
            bfr[nt] = *(const bf16x8*)(BT +
                (size_t)((wave * NT + nt) * 16 + lr) * 128 + k0 + lk);
        #pragma unroll
        for (int mt = 0; mt < 2; ++mt) {
            bf16x8 afr = *(const bf16x8*)(&a4_s[ksi][(mt * 16 + lr) * 40 + lk]);
            #pragma unroll
            for (int nt = 0; nt < NT; ++nt)
                acc[mt][nt] = __builtin_amdgcn_mfma_f32_16x16x32_bf16(
                    afr, bfr[nt], acc[mt][nt], 0, 0, 0);
        }
    }
    int col0 = wave * NT * 16;
    #pragma unroll
    for (int mt = 0; mt < 2; ++mt) {
        int gr0 = row0 + mt * 16 + (lane >> 4) * 4;
        #pragma unroll
        for (int nt = 0; nt < NT; ++nt) {
            int gc = col0 + nt * 16 + lr;
            #pragma unroll
            for (int i = 0; i < 4; ++i) {
                int gr = gr0 + i;
                if (gr < N_NODES && gc < Nout)
                    Cout[(size_t)gr * Nout + gc] = f2bf(acc[mt][nt][i]);
            }
        }
    }
}

__global__ __launch_bounds__(256) void fused_ag2(const uint* __restrict__ sup,
                                                 const int2* __restrict__ rsp2,
                                                 const uint* __restrict__ edges,
                                                 const float* __restrict__ bias,
                                                 const ushort* __restrict__ BT,
                                                 ushort* __restrict__ Cout) {
    fused_body<2>(sup, rsp2, edges, bias, BT, 128, Cout);
}

__global__ __launch_bounds__(256) void fused_ag3(const uint* __restrict__ sup,
                                                 const int2* __restrict__ rsp2,
                                                 const uint* __restrict__ edges,
                                                 const float* __restrict__ bias,
                                                 const ushort* __restrict__ BT,
                                                 ushort* __restrict__ Cout) {
    fused_body<1>(sup, rsp2, edges, bias, BT, 64, Cout);   // F=64, cols 40..63 zero
}

// ---------------------------------------------------------------------------
// Layer 3 aggregation + bias + log_softmax, flattened-stream, scalarized
// records (same engine). sup3 is F=64 natural layout (cols 40..63 zero).

#define GATHER_L(P, R) do { \
    _Pragma("unroll") \
    for (int _j = 0; _j < 16; ++_j) { \
        uint _idx = R[_j] & 0xffffu; \
        _idx = (_idx < N_NODES) ? _idx : (N_NODES - 1); \
        P[_j] = __uint_as_float((uint)sup[(size_t)_idx * 64 + lane] << 16); \
    } \
} while (0)

#define FLUSH_L() do { \
    int _node = nfirst + cur; \
    float _v = (lane < 40) ? acc1 + bl : -INFINITY; \
    float _m = _v; \
    _Pragma("unroll") \
    for (int _o = 32; _o; _o >>= 1) _m = fmaxf(_m, __shfl_xor(_m, _o, 64)); \
    float _ex = (lane < 40) ? expf(_v - _m) : 0.f; \
    float _s = _ex; \
    _Pragma("unroll") \
    for (int _o = 32; _o; _o >>= 1) _s += __shfl_xor(_s, _o, 64); \
    float _ls = logf(_s); \
    if (lane < 40 && _node < N_NODES) \
        out[(size_t)_node * 40 + lane] = _v - _m - _ls; \
    acc1 = 0.f; \
    ++cur; \
    e_cur = (cur < 8) ? e_s[wave][cur + 1] : 0x7fffffff; \
} while (0)

#define FMA_L(QB, P, R) do { \
    _Pragma("unroll") \
    for (int _g = 0; _g < 2; ++_g) { \
        int _qg = (QB) + _g * 8; \
        while (cur < 8 && _qg >= e_cur) FLUSH_L(); \
        if (_qg < QE) { \
            _Pragma("unroll") \
            for (int _j = 0; _j < 8; ++_j) \
                acc1 += P[_g * 8 + _j] * \
                        __uint_as_float(R[_g * 8 + _j] & 0xffff0000u); \
        } \
    } \
} while (0)

__global__ __launch_bounds__(256) void agg_lsm(const ushort* __restrict__ sup,
                                               const int2* __restrict__ rsp2,
                                               const uint* __restrict__ edges,
                                               const float* __restrict__ bias,
                                               float* __restrict__ out) {
    __shared__ int e_s[4][9];
    int tid = threadIdx.x;
    int wave = tid >> 6, lane = tid & 63;
    int nfirst = blockIdx.x * 32 + wave * 8;
    float bl = (lane < 40) ? bias[lane] : 0.f;
    if (lane < 8) {
        int nd = nfirst + lane; if (nd >= N_NODES) nd = N_NODES - 1;
        int2 t = rsp2[nd];
        e_s[wave][lane + 1] = t.y;
        if (lane == 0) e_s[wave][0] = t.x;
    }
    __syncthreads();
    int Q = e_s[wave][0], QE = e_s[wave][8];
    int cur = 0, e_cur = e_s[wave][1];
    float acc1 = 0.f;

    uint ra[16], rb[16], rc[16];
    float pa[16], pb[16];
    int q = Q;
    LDREC_S(ra, q);
    GATHER_L(pa, ra);
    LDREC_S(rb, q + 16);
    while (q < QE) {
        GATHER_L(pb, rb); LDREC_S(rc, q + 32); FMA_L(q, pa, ra);
        q += 16; if (q >= QE) break;
        GATHER_L(pa, rc); LDREC_S(ra, q + 32); FMA_L(q, pb, rb);
        q += 16; if (q >= QE) break;
        GATHER_L(pb, ra); LDREC_S(rb, q + 32); FMA_L(q, pa, rc);
        q += 16; if (q >= QE) break;
        GATHER_L(pa, rb); LDREC_S(rc, q + 32); FMA_L(q, pb, ra);
        q += 16; if (q >= QE) break;
        GATHER_L(pb, rc); LDREC_S(ra, q + 32); FMA_L(q, pa, rb);
        q += 16; if (q >= QE) break;
        GATHER_L(pa, ra); LDREC_S(rb, q + 32); FMA_L(q, pb, rc);
        q += 16;
    }
    while (cur < 8) FLUSH_L();
}

// ---------------------------------------------------------------------------
extern "C" void kernel_launch(void* const* d_in, const int* in_sizes, int n_in,
                              void* d_out, int out_size, void* d_ws, size_t ws_size,
                              hipStream_t stream) {
    const float* x   = (const float*)d_in[0];
    const float* ew  = (const float*)d_in[1];
    const float* W1  = (const float*)d_in[2];
    const float* b1  = (const float*)d_in[3];
    const float* W2  = (const float*)d_in[4];
    const float* b2  = (const float*)d_in[5];
    const float* W3  = (const float*)d_in[6];
    const float* b3  = (const float*)d_in[7];
    const int* esrc  = (const int*)d_in[8];
    const int* edst  = (const int*)d_in[9];
    float* out = (float*)d_out;

    char* ws = (char*)d_ws;
    size_t off = 0;
    auto alloc = [&](size_t bytes) {
        size_t cur = off;
        off += (bytes + 255) & ~(size_t)255;
        return cur;
    };
    int* bucket_cnt = (int*)(ws + alloc(256 * sizeof(int)));
    int2* rsp2   = (int2*)(ws + alloc((size_t)N_NODES * sizeof(int2)));          // 400 KB
    uint* edges  = (uint*)(ws + alloc((size_t)NBUCK * BUCK_WIN * sizeof(uint))); // 4.6 MB
    int2* staging = (int2*)(ws + alloc((size_t)NBUCK * BUCK_CAP * sizeof(int2))); // 6.4 MB
    ushort* BT1  = (ushort*)(ws + alloc(128 * 256 * 2));
    ushort* BT2  = (ushort*)(ws + alloc(128 * 128 * 2));
    ushort* BT3  = (ushort*)(ws + alloc(64 * 128 * 2));
    char* Sreg   = ws + alloc((size_t)N_NODES * 128 * 2);       // 12.8 MB
    char* Hreg   = ws + alloc((size_t)N_NODES * 128 * 2);       // 12.8 MB
    (void)alloc((size_t)66000 * 128 * 2);   // clamp-gather slack past Hreg

    ushort* supA = (ushort*)Sreg;                  // gemm1 out
    ushort* supB = (ushort*)Hreg;                  // fused ag2 out
    ushort* sup3 = (ushort*)Sreg;                  // fused ag3 out (supA dead), F=64

    hipMemsetAsync(bucket_cnt, 0, 256 * sizeof(int), stream);
    // K1: edge binning || weight conversion
    binA_cvtw<<<BINA_BLOCKS + CVTW_BLOCKS, 256, 0, stream>>>(
        esrc, edst, ew, bucket_cnt, staging, N_EDGES, W1, W2, W3, BT1, BT2, BT3);
    // K2: per-bucket scan+scatter (fixed windows) || GEMM1
    scan_gemm1<<<NBUCK + GEMM_BLOCKS, 256, 0, stream>>>(
        bucket_cnt, staging, rsp2, edges, x, BT1, supA);
    // K3: [agg1 + b1 + relu] -> GEMM x BT2 -> supB
    fused_ag2<<<TILE_BLOCKS, 256, 0, stream>>>(
        (const uint*)supA, rsp2, edges, b1, BT2, supB);
    // K4: [agg2 + b2 + relu] -> GEMM x BT3 -> sup3 (F=64, cols 40..63 zero)
    fused_ag3<<<TILE_BLOCKS, 256, 0, stream>>>(
        (const uint*)supB, rsp2, edges, b2, BT3, sup3);
    // K5: agg3 + b3 + log_softmax -> out (flattened stream)
    agg_lsm<<<TILE_BLOCKS, 256, 0, stream>>>(sup3, rsp2, edges, b3, out);
}